// Round 9
// baseline (448.589 us; speedup 1.0000x reference)
//
#include <hip/hip_runtime.h>
#include <hip/hip_bf16.h>
#include <math.h>

#define N_GENES 20000
#define N_CELLS 1024
#define FM_DIM  512
#define EMB     512
#define N_EDGES 640000
#define LN_EPS  1e-5f
#define SCAN_B  79   // ceil(20000/256)
#define IDX_CAP 2560 // LDS index-stage capacity (avg block load = 1024)

typedef __attribute__((ext_vector_type(8))) short bf8;
typedef __attribute__((ext_vector_type(4))) float f32x4;

__device__ __forceinline__ float bflo(unsigned v) { return __uint_as_float(v << 16); }
__device__ __forceinline__ float bfhi(unsigned v) { return __uint_as_float(v & 0xffff0000u); }
__device__ __forceinline__ unsigned short f2bf(float f) {
    unsigned u = __float_as_uint(f);
    return (unsigned short)((u + 0x7fffu + ((u >> 16) & 1u)) >> 16);  // RNE
}
__device__ __forceinline__ unsigned packbf(float x, float y) {
    return (unsigned)f2bf(x) | ((unsigned)f2bf(y) << 16);
}
__device__ __forceinline__ unsigned addbf2(unsigned x, unsigned y) {
    return packbf(bflo(x) + bflo(y), bfhi(x) + bfhi(y));
}
__device__ __forceinline__ uint4 pack8(float4 a, float4 b) {
    uint4 o;
    o.x = packbf(a.x, a.y);
    o.y = packbf(a.z, a.w);
    o.z = packbf(b.x, b.y);
    o.w = packbf(b.z, b.w);
    return o;
}

// async global->LDS, 16 B per lane. LDS dest must be wave-uniform base + lane*16.
__device__ __forceinline__ void gload16(const unsigned short* g, unsigned short* l) {
    __builtin_amdgcn_global_load_lds(
        (const __attribute__((address_space(1))) unsigned int*)g,
        (__attribute__((address_space(3))) unsigned int*)l, 16, 0, 0);
}

// ---------------------------------------------------------------------------
// Fused: x_exp cvt (grid-stride) + 8-weight cvt + edge count+slot, one launch.
// ---------------------------------------------------------------------------
__global__ __launch_bounds__(256) void k_cvtcnt(const float4* __restrict__ xe,
                                                const float4* s0, const float4* s1,
                                                const float4* s2, const float4* s3,
                                                const float4* s4, const float4* s5,
                                                const float4* s6, const float4* s7,
                                                uint4* __restrict__ Xe,
                                                uint4* __restrict__ Wb,
                                                const int* __restrict__ edst,
                                                int* __restrict__ cnt,
                                                unsigned char* __restrict__ eslot) {
    if (blockIdx.x < 2048) {
        for (int i = blockIdx.x * 256 + threadIdx.x; i < 2560000 + 327680;
             i += 2048 * 256) {
            if (i < 2560000) {
                Xe[i] = pack8(xe[2 * i], xe[2 * i + 1]);
            } else {
                int w = i - 2560000;
                const float4* src; int off;
                if (w < 65536)       { src = s0; off = w; }
                else if (w < 131072) { src = s1; off = w - 65536; }
                else if (w < 163840) { src = s2; off = w - 131072; }
                else if (w < 196608) { src = s3; off = w - 163840; }
                else if (w < 229376) { src = s4; off = w - 196608; }
                else if (w < 262144) { src = s5; off = w - 229376; }
                else if (w < 294912) { src = s6; off = w - 262144; }
                else                 { src = s7; off = w - 294912; }
                Wb[w] = pack8(src[2 * off], src[2 * off + 1]);
            }
        }
    } else {
        int e = (blockIdx.x - 2048) * 256 + threadIdx.x;
        if (e < N_EDGES) {
            int old = atomicAdd(&cnt[edst[e]], 1);
            eslot[e] = (unsigned char)old;   // max degree ~Poisson(32) << 256
        }
    }
}

// ---------------------------------------------------------------------------
// CSR: hierarchical scan (byte-identical to r15-r19)
// ---------------------------------------------------------------------------
__global__ __launch_bounds__(256) void k_scan1(const int* __restrict__ cnt,
                                               int* __restrict__ row_ptr,
                                               int* __restrict__ bsum) {
    __shared__ int wsum[4];
    int b = blockIdx.x, t = threadIdx.x;
    int i = b * 256 + t;
    int v = (i < N_GENES) ? cnt[i] : 0;
    int lane = t & 63, wv = t >> 6;
    int x = v;
#pragma unroll
    for (int off = 1; off < 64; off <<= 1) {
        int y = __shfl_up(x, off);
        if (lane >= off) x += y;
    }
    if (lane == 63) wsum[wv] = x;
    __syncthreads();
    if (t == 0) {
        int s = 0;
        for (int w = 0; w < 4; ++w) { int tmp = wsum[w]; wsum[w] = s; s += tmp; }
    }
    __syncthreads();
    int excl = x - v + wsum[wv];
    if (i < N_GENES) row_ptr[i] = excl;
    if (t == 255) bsum[b] = excl + v;
}

__global__ void k_scan2(const int* __restrict__ bsum, int* __restrict__ boff) {
    __shared__ int wsum[2];
    int t = threadIdx.x;                      // 128
    int v = (t < SCAN_B) ? bsum[t] : 0;
    int lane = t & 63, wv = t >> 6;
    int x = v;
#pragma unroll
    for (int off = 1; off < 64; off <<= 1) {
        int y = __shfl_up(x, off);
        if (lane >= off) x += y;
    }
    if (lane == 63) wsum[wv] = x;
    __syncthreads();
    int add = (wv == 1) ? wsum[0] : 0;
    int excl = x - v + add;
    if (t < SCAN_B) boff[t] = excl;
    if (t == SCAN_B) boff[SCAN_B] = excl;
}

__global__ __launch_bounds__(256) void k_scan3(int* __restrict__ row_ptr,
                                               const int* __restrict__ boff) {
    int i = blockIdx.x * 256 + threadIdx.x;
    if (i < N_GENES) row_ptr[i] += boff[i >> 8];
    if (blockIdx.x == 0 && threadIdx.x == 0) row_ptr[N_GENES] = boff[SCAN_B];
}

// ---------------------------------------------------------------------------
// L0 PAIR GEMM + ATOMIC-FREE CSR-FILL in one dispatch. grid (8, 473).
// v7: 3-deep pipelined LDS (48 KB) + counted vmcnt(8) (best measured, R7).
// ---------------------------------------------------------------------------
__global__ __launch_bounds__(256) void k_gemm_pf(const unsigned short* __restrict__ A,
                                                 const unsigned short* __restrict__ Wl,
                                                 const unsigned short* __restrict__ Wr,
                                                 unsigned short* __restrict__ C0,
                                                 unsigned short* __restrict__ C1,
                                                 int M, int K,
                                                 const int* __restrict__ e_src,
                                                 const int* __restrict__ e_dst,
                                                 const int* __restrict__ row_ptr,
                                                 const unsigned char* __restrict__ eslot,
                                                 int* __restrict__ csr) {
    __shared__ __attribute__((aligned(16))) unsigned short As[3][128][32];
    __shared__ __attribute__((aligned(16))) unsigned short Bs[3][128][32];
    if (blockIdx.y >= 160) {   // fill path: no atomics, no barriers
        int e = ((blockIdx.y - 160) * 8 + blockIdx.x) * 256 + threadIdx.x;
        if (e < N_EDGES) {
            int d = e_dst[e];
            csr[row_ptr[d] + (int)eslot[e]] = e_src[e];
        }
        return;
    }
    int m0 = (blockIdx.x * 20 + (blockIdx.y >> 3)) * 128;
    if (m0 >= M) return;
    int sel = blockIdx.y & 7;
    const unsigned short* W = (sel < 4) ? Wl : Wr;
    unsigned short* Cp = (sel < 4) ? C0 : C1;
    int n0 = (sel & 3) * 128;
    int tid = threadIdx.x;
    int lane = tid & 63;
    int w = tid >> 6, wr = w >> 1, wc = w & 1;

    int srow = tid >> 2, sch = tid & 3;
    int rA0 = min(m0 + srow, M - 1);
    int rA1 = min(m0 + srow + 64, M - 1);
    const unsigned short* gA0 = A + (size_t)rA0 * K + sch * 8;
    const unsigned short* gA1 = A + (size_t)rA1 * K + sch * 8;
    const unsigned short* gB0 = W + (size_t)(n0 + srow) * K + sch * 8;
    const unsigned short* gB1 = W + (size_t)(n0 + srow + 64) * K + sch * 8;

    f32x4 acc[4][4];
#pragma unroll
    for (int i = 0; i < 4; ++i)
#pragma unroll
        for (int j = 0; j < 4; ++j) acc[i][j] = (f32x4){0.f, 0.f, 0.f, 0.f};

    auto stage = [&](int b, int k0) {   // literal b only -> static after inline
        unsigned short* Ab = &As[b][0][0];
        unsigned short* Bb = &Bs[b][0][0];
        gload16(gA0 + k0, Ab + tid * 8);
        gload16(gA1 + k0, Ab + 64 * 32 + tid * 8);
        gload16(gB0 + k0, Bb + tid * 8);
        gload16(gB1 + k0, Bb + 64 * 32 + tid * 8);
    };
    auto compute = [&](int b) {
        const unsigned short* Ab = &As[b][0][0];
        const unsigned short* Bb = &Bs[b][0][0];
        bf8 af[4], bff[4];
#pragma unroll
        for (int f = 0; f < 4; ++f) {
            af[f]  = *(const bf8*)(Ab + (wr * 64 + f * 16 + (lane & 15)) * 32 + (lane >> 4) * 8);
            bff[f] = *(const bf8*)(Bb + (wc * 64 + f * 16 + (lane & 15)) * 32 + (lane >> 4) * 8);
        }
#pragma unroll
        for (int i = 0; i < 4; ++i)
#pragma unroll
            for (int j = 0; j < 4; ++j)
                acc[i][j] = __builtin_amdgcn_mfma_f32_16x16x32_bf16(af[i], bff[j],
                                                                    acc[i][j], 0, 0, 0);
    };

#define PF_STEP(CB, SB, ST, VM)                                  \
    stage(SB, (ST) * 32);                                        \
    asm volatile("s_waitcnt vmcnt(" #VM ")" ::: "memory");       \
    __builtin_amdgcn_s_barrier();                                \
    __builtin_amdgcn_sched_barrier(0);                           \
    compute(CB);                                                 \
    asm volatile("s_waitcnt lgkmcnt(0)" ::: "memory");           \
    __builtin_amdgcn_s_barrier();                                \
    __builtin_amdgcn_sched_barrier(0);

    const int NT = K / 32;   // 32 for K=1024; main loop assumes NT % 3 == 2
    stage(0, 0);
    stage(1, 32);
    for (int t = 0; t + 4 < NT; t += 3) {
        PF_STEP(0, 2, t + 2, 8)
        PF_STEP(1, 0, t + 3, 8)
        PF_STEP(2, 1, t + 4, 8)
    }
    // peel: tiles NT-2 (buf 0), NT-1 (buf 1); no more staging
    asm volatile("s_waitcnt vmcnt(4)" ::: "memory");
    __builtin_amdgcn_s_barrier();
    __builtin_amdgcn_sched_barrier(0);
    compute(0);
    asm volatile("s_waitcnt lgkmcnt(0)" ::: "memory");
    __builtin_amdgcn_s_barrier();
    __builtin_amdgcn_sched_barrier(0);
    asm volatile("s_waitcnt vmcnt(0)" ::: "memory");
    __builtin_amdgcn_s_barrier();
    __builtin_amdgcn_sched_barrier(0);
    compute(1);
#undef PF_STEP

#pragma unroll
    for (int i = 0; i < 4; ++i) {
        int rb = m0 + wr * 64 + i * 16 + (lane >> 4) * 4;
#pragma unroll
        for (int j = 0; j < 4; ++j) {
            int cc = n0 + wc * 64 + j * 16 + (lane & 15);
#pragma unroll
            for (int e = 0; e < 4; ++e) {
                int r = rb + e;
                if (r < M) Cp[(size_t)r * EMB + cc] = f2bf(acc[i][j][e]);
            }
        }
    }
}

// ---------------------------------------------------------------------------
// FUSED-ADD GEMM, XCD-partitioned: grid (8, 80). BK=64 single-buffer (R6).
// ---------------------------------------------------------------------------
__global__ __launch_bounds__(256) void k_gemm_fu(const unsigned short* __restrict__ A,
                                                 const unsigned short* __restrict__ A2,
                                                 const unsigned short* __restrict__ W,
                                                 unsigned short* __restrict__ Cp,
                                                 int M, int K) {
    __shared__ __attribute__((aligned(16))) unsigned short As[2][128][32];
    __shared__ __attribute__((aligned(16))) unsigned short Bs[2][128][32];
    int m0 = (blockIdx.x * 20 + (blockIdx.y >> 2)) * 128;
    if (m0 >= M) return;
    int n0 = (blockIdx.y & 3) * 128;
    int tid = threadIdx.x;
    int lane = tid & 63;
    int w = tid >> 6, wr = w >> 1, wc = w & 1;

    int srow = tid >> 2, sch = tid & 3;
    int rA0 = min(m0 + srow, M - 1);
    int rA1 = min(m0 + srow + 64, M - 1);
    const unsigned short* gA0 = A + (size_t)rA0 * K + sch * 8;
    const unsigned short* gA1 = A + (size_t)rA1 * K + sch * 8;
    const unsigned short* hA0 = A2 + (size_t)rA0 * K + sch * 8;
    const unsigned short* hA1 = A2 + (size_t)rA1 * K + sch * 8;
    const unsigned short* gB0 = W + (size_t)(n0 + srow) * K + sch * 8;
    const unsigned short* gB1 = W + (size_t)(n0 + srow + 64) * K + sch * 8;

    f32x4 acc[4][4];
#pragma unroll
    for (int i = 0; i < 4; ++i)
#pragma unroll
        for (int j = 0; j < 4; ++j) acc[i][j] = (f32x4){0.f, 0.f, 0.f, 0.f};

    auto compute = [&](int b) {
        const unsigned short* Ab = &As[b][0][0];
        const unsigned short* Bb = &Bs[b][0][0];
        bf8 af[4], bff[4];
#pragma unroll
        for (int f = 0; f < 4; ++f) {
            af[f]  = *(const bf8*)(Ab + (wr * 64 + f * 16 + (lane & 15)) * 32 + (lane >> 4) * 8);
            bff[f] = *(const bf8*)(Bb + (wc * 64 + f * 16 + (lane & 15)) * 32 + (lane >> 4) * 8);
        }
#pragma unroll
        for (int i = 0; i < 4; ++i)
#pragma unroll
            for (int j = 0; j < 4; ++j)
                acc[i][j] = __builtin_amdgcn_mfma_f32_16x16x32_bf16(af[i], bff[j],
                                                                    acc[i][j], 0, 0, 0);
    };

    for (int k0 = 0; k0 < K; k0 += 64) {
        uint4 x00 = *(const uint4*)(gA0 + k0);
        uint4 y00 = *(const uint4*)(hA0 + k0);
        uint4 x10 = *(const uint4*)(gA1 + k0);
        uint4 y10 = *(const uint4*)(hA1 + k0);
        uint4 x01 = *(const uint4*)(gA0 + k0 + 32);
        uint4 y01 = *(const uint4*)(hA0 + k0 + 32);
        uint4 x11 = *(const uint4*)(gA1 + k0 + 32);
        uint4 y11 = *(const uint4*)(hA1 + k0 + 32);
        uint4 a00, a10, a01, a11;
        a00.x = addbf2(x00.x, y00.x); a00.y = addbf2(x00.y, y00.y);
        a00.z = addbf2(x00.z, y00.z); a00.w = addbf2(x00.w, y00.w);
        a10.x = addbf2(x10.x, y10.x); a10.y = addbf2(x10.y, y10.y);
        a10.z = addbf2(x10.z, y10.z); a10.w = addbf2(x10.w, y10.w);
        a01.x = addbf2(x01.x, y01.x); a01.y = addbf2(x01.y, y01.y);
        a01.z = addbf2(x01.z, y01.z); a01.w = addbf2(x01.w, y01.w);
        a11.x = addbf2(x11.x, y11.x); a11.y = addbf2(x11.y, y11.y);
        a11.z = addbf2(x11.z, y11.z); a11.w = addbf2(x11.w, y11.w);
        __syncthreads();
        *(uint4*)(&As[0][0][0] + tid * 8)       = a00;
        *(uint4*)(&As[0][64][0] + tid * 8)      = a10;
        *(uint4*)(&As[1][0][0] + tid * 8)       = a01;
        *(uint4*)(&As[1][64][0] + tid * 8)      = a11;
        gload16(gB0 + k0,      &Bs[0][0][0] + tid * 8);
        gload16(gB1 + k0,      &Bs[0][64][0] + tid * 8);
        gload16(gB0 + k0 + 32, &Bs[1][0][0] + tid * 8);
        gload16(gB1 + k0 + 32, &Bs[1][64][0] + tid * 8);
        __syncthreads();
        compute(0);
        compute(1);
    }

#pragma unroll
    for (int i = 0; i < 4; ++i) {
        int rb = m0 + wr * 64 + i * 16 + (lane >> 4) * 4;
#pragma unroll
        for (int j = 0; j < 4; ++j) {
            int cc = n0 + wc * 64 + j * 16 + (lane & 15);
#pragma unroll
            for (int e = 0; e < 4; ++e) {
                int r = rb + e;
                if (r < M) Cp[(size_t)r * EMB + cc] = f2bf(acc[i][j][e]);
            }
        }
    }
}

// ---------------------------------------------------------------------------
// PAIR GEMM, XCD-partitioned: grid (8, 160). BK=64 single-buffer (R6).
// Used for both the L1 pair (was k_gemm_3's pair part) and the final pair.
// ---------------------------------------------------------------------------
__global__ __launch_bounds__(256) void k_gemm_p(const unsigned short* __restrict__ A,
                                                const unsigned short* __restrict__ Wl,
                                                const unsigned short* __restrict__ Wr,
                                                unsigned short* __restrict__ C0,
                                                unsigned short* __restrict__ C1,
                                                int M, int K) {
    __shared__ __attribute__((aligned(16))) unsigned short As[2][128][32];
    __shared__ __attribute__((aligned(16))) unsigned short Bs[2][128][32];
    int m0 = (blockIdx.x * 20 + (blockIdx.y >> 3)) * 128;
    if (m0 >= M) return;
    int sel = blockIdx.y & 7;
    const unsigned short* W = (sel < 4) ? Wl : Wr;
    unsigned short* Cp = (sel < 4) ? C0 : C1;
    int n0 = (sel & 3) * 128;
    int tid = threadIdx.x;
    int lane = tid & 63;
    int w = tid >> 6, wr = w >> 1, wc = w & 1;

    int srow = tid >> 2, sch = tid & 3;
    int rA0 = min(m0 + srow, M - 1);
    int rA1 = min(m0 + srow + 64, M - 1);
    const unsigned short* gA0 = A + (size_t)rA0 * K + sch * 8;
    const unsigned short* gA1 = A + (size_t)rA1 * K + sch * 8;
    const unsigned short* gB0 = W + (size_t)(n0 + srow) * K + sch * 8;
    const unsigned short* gB1 = W + (size_t)(n0 + srow + 64) * K + sch * 8;

    f32x4 acc[4][4];
#pragma unroll
    for (int i = 0; i < 4; ++i)
#pragma unroll
        for (int j = 0; j < 4; ++j) acc[i][j] = (f32x4){0.f, 0.f, 0.f, 0.f};

    auto compute = [&](int b) {
        const unsigned short* Ab = &As[b][0][0];
        const unsigned short* Bb = &Bs[b][0][0];
        bf8 af[4], bff[4];
#pragma unroll
        for (int f = 0; f < 4; ++f) {
            af[f]  = *(const bf8*)(Ab + (wr * 64 + f * 16 + (lane & 15)) * 32 + (lane >> 4) * 8);
            bff[f] = *(const bf8*)(Bb + (wc * 64 + f * 16 + (lane & 15)) * 32 + (lane >> 4) * 8);
        }
#pragma unroll
        for (int i = 0; i < 4; ++i)
#pragma unroll
            for (int j = 0; j < 4; ++j)
                acc[i][j] = __builtin_amdgcn_mfma_f32_16x16x32_bf16(af[i], bff[j],
                                                                    acc[i][j], 0, 0, 0);
    };

    for (int k0 = 0; k0 < K; k0 += 64) {
        __syncthreads();
        gload16(gA0 + k0,      &As[0][0][0] + tid * 8);
        gload16(gA1 + k0,      &As[0][64][0] + tid * 8);
        gload16(gA0 + k0 + 32, &As[1][0][0] + tid * 8);
        gload16(gA1 + k0 + 32, &As[1][64][0] + tid * 8);
        gload16(gB0 + k0,      &Bs[0][0][0] + tid * 8);
        gload16(gB1 + k0,      &Bs[0][64][0] + tid * 8);
        gload16(gB0 + k0 + 32, &Bs[1][0][0] + tid * 8);
        gload16(gB1 + k0 + 32, &Bs[1][64][0] + tid * 8);
        __syncthreads();
        compute(0);
        compute(1);
    }

#pragma unroll
    for (int i = 0; i < 4; ++i) {
        int rb = m0 + wr * 64 + i * 16 + (lane >> 4) * 4;
#pragma unroll
        for (int j = 0; j < 4; ++j) {
            int cc = n0 + wc * 64 + j * 16 + (lane & 15);
#pragma unroll
            for (int e = 0; e < 4; ++e) {
                int r = rb + e;
                if (r < M) Cp[(size_t)r * EMB + cc] = f2bf(acc[i][j][e]);
            }
        }
    }
}

// ---------------------------------------------------------------------------
// Sage body v2, XCD-SLICED: slice (128 B cols) pinned to XCD via grid x-dim.
// Block = 32 nodes x 8 lanes; lane l covers uint4 word slice*8+l (16 B).
// ---------------------------------------------------------------------------
template <int OUTF32>
__device__ __forceinline__ void sage_body(const unsigned short* yl,
                                          const unsigned short* yr,
                                          const float* bl,
                                          const int* row_ptr,
                                          const int* csr,
                                          void* outp, int slice, int nblk,
                                          int* sIdx) {
    int g = threadIdx.x >> 3;            // node in block: 0..31
    int l = threadIdx.x & 7;             // lane in group: 0..7
    int node = nblk * 32 + g;
    int w = slice * 8 + l;               // uint4 word index 0..63
    int s32 = row_ptr[nblk * 32];
    int e32 = row_ptr[nblk * 32 + 32];
    int nIdx = e32 - s32;
    bool lds_ok = (nIdx <= IDX_CAP);
    if (lds_ok) {
        for (int i = threadIdx.x; i < nIdx; i += 256) sIdx[i] = csr[s32 + i];
    }
    __syncthreads();
    int s = row_ptr[node], e = row_ptr[node + 1];
    int deg = e - s;
    const char* Yb = (const char*)yl;    // row stride 1024 B
    unsigned lb = (unsigned)(w << 4);
    float ac[8];
#pragma unroll
    for (int q = 0; q < 8; ++q) ac[q] = 0.f;
    if (lds_ok) {
        int lp = s - s32;
        int p = 0;
        for (; p + 8 <= deg; p += 8) {
            int j[8];
#pragma unroll
            for (int q = 0; q < 8; ++q) j[q] = sIdx[lp + p + q];
            uint4 v[8];
#pragma unroll
            for (int q = 0; q < 8; ++q)
                v[q] = *(const uint4*)(Yb + (((unsigned)j[q] << 10) + lb));
#pragma unroll
            for (int q = 0; q < 8; ++q) {
                ac[0] += bflo(v[q].x); ac[1] += bfhi(v[q].x);
                ac[2] += bflo(v[q].y); ac[3] += bfhi(v[q].y);
                ac[4] += bflo(v[q].z); ac[5] += bfhi(v[q].z);
                ac[6] += bflo(v[q].w); ac[7] += bfhi(v[q].w);
            }
        }
        for (; p < deg; ++p) {
            int j = sIdx[lp + p];
            uint4 v = *(const uint4*)(Yb + (((unsigned)j << 10) + lb));
            ac[0] += bflo(v.x); ac[1] += bfhi(v.x);
            ac[2] += bflo(v.y); ac[3] += bfhi(v.y);
            ac[4] += bflo(v.z); ac[5] += bfhi(v.z);
            ac[6] += bflo(v.w); ac[7] += bfhi(v.w);
        }
    } else {  // overflow fallback (never expected for this input)
        for (int p = s; p < e; ++p) {
            int j = csr[p];
            uint4 v = *(const uint4*)(Yb + (((unsigned)j << 10) + lb));
            ac[0] += bflo(v.x); ac[1] += bfhi(v.x);
            ac[2] += bflo(v.y); ac[3] += bfhi(v.y);
            ac[4] += bflo(v.z); ac[5] += bfhi(v.z);
            ac[6] += bflo(v.w); ac[7] += bfhi(v.w);
        }
    }
    float inv = 1.f / fmaxf((float)deg, 1.f);
    uint4 vr = ((const uint4*)yr)[(size_t)node * 64 + w];
    float4 bA = ((const float4*)bl)[2 * w];
    float4 bB = ((const float4*)bl)[2 * w + 1];
    float o[8];
    o[0] = ac[0] * inv + bA.x + bflo(vr.x);
    o[1] = ac[1] * inv + bA.y + bfhi(vr.x);
    o[2] = ac[2] * inv + bA.z + bflo(vr.y);
    o[3] = ac[3] * inv + bA.w + bfhi(vr.y);
    o[4] = ac[4] * inv + bB.x + bflo(vr.z);
    o[5] = ac[5] * inv + bB.y + bfhi(vr.z);
    o[6] = ac[6] * inv + bB.z + bflo(vr.w);
    o[7] = ac[7] * inv + bB.w + bfhi(vr.w);
#pragma unroll
    for (int q = 0; q < 8; ++q) o[q] = o[q] > 0.f ? o[q] : expm1f(o[q]);
    if (OUTF32) {
        float4* O = (float4*)outp;
        O[(size_t)node * 128 + 2 * w]     = make_float4(o[0], o[1], o[2], o[3]);
        O[(size_t)node * 128 + 2 * w + 1] = make_float4(o[4], o[5], o[6], o[7]);
    } else {
        uint4 ov;
        ov.x = packbf(o[0], o[1]);
        ov.y = packbf(o[2], o[3]);
        ov.z = packbf(o[4], o[5]);
        ov.w = packbf(o[6], o[7]);
        ((uint4*)outp)[(size_t)node * 64 + w] = ov;
    }
}

// grid (8, 625): x = slice/XCD, y = node block (32 nodes)
template <int OUTF32>
__global__ __launch_bounds__(256) void k_sage_b(const unsigned short* __restrict__ yl,
                                                const unsigned short* __restrict__ yr,
                                                const float* __restrict__ bl,
                                                const int* __restrict__ row_ptr,
                                                const int* __restrict__ csr,
                                                void* __restrict__ outp) {
    __shared__ int sIdx[IDX_CAP];
    sage_body<OUTF32>(yl, yr, bl, row_ptr, csr, outp, blockIdx.x, blockIdx.y, sIdx);
}

// ---------------------------------------------------------------------------
// MERGED: sage0 (C0,C1 -> actA, h1) + FOUNDATION GEMM Wf (x_found -> F0).
// grid (8, 705): y < 625 -> sage(slice=x, nblk=y); y >= 625 -> Wf GEMM block
// (independent of h1 -- overlaps the latency-bound gather with MFMA work).
// LDS: single 32 KB union (GEMM As/Bs = smem[0..3]; sage sIdx aliases smem).
// 32 KB -> 5 blocks/CU = 20 waves, matching sage's measured ~59% occupancy.
// ---------------------------------------------------------------------------
__global__ __launch_bounds__(256) void k_sagewf(const unsigned short* __restrict__ C0,
                                                const unsigned short* __restrict__ C1,
                                                const float* __restrict__ bl0,
                                                const int* __restrict__ row_ptr,
                                                const int* __restrict__ csr,
                                                unsigned short* __restrict__ actA,
                                                const float* __restrict__ A2,
                                                const unsigned short* __restrict__ Wf,
                                                unsigned short* __restrict__ CF,
                                                int M) {
    __shared__ __attribute__((aligned(16))) unsigned short smem[4][128][32];  // 32 KB
    if (blockIdx.y < 625) {
        sage_body<0>(C0, C1, bl0, row_ptr, csr, actA, blockIdx.x, blockIdx.y,
                     (int*)&smem[0][0][0]);
        return;
    }
    // ---- Wf single GEMM (fp32 A reg-staged), BK=64, R6 structure ----
    const int K = 512;
    int y2 = blockIdx.y - 625;                    // [0, 80)
    int m0 = (blockIdx.x * 20 + (y2 >> 2)) * 128;
    if (m0 >= M) return;
    int n0 = (y2 & 3) * 128;
    int tid = threadIdx.x;
    int lane = tid & 63;
    int w = tid >> 6, wr = w >> 1, wc = w & 1;

    int srow = tid >> 2, sch = tid & 3;
    int rA0 = min(m0 + srow, M - 1);
    int rA1 = min(m0 + srow + 64, M - 1);
    const float* fA0 = A2 + (size_t)rA0 * K + sch * 8;
    const float* fA1 = A2 + (size_t)rA1 * K + sch * 8;
    const unsigned short* gB0 = Wf + (size_t)(n0 + srow) * K + sch * 8;
    const unsigned short* gB1 = Wf + (size_t)(n0 + srow + 64) * K + sch * 8;

    f32x4 acc[4][4];
#pragma unroll
    for (int i = 0; i < 4; ++i)
#pragma unroll
        for (int j = 0; j < 4; ++j) acc[i][j] = (f32x4){0.f, 0.f, 0.f, 0.f};

    auto compute = [&](int b) {   // A = smem[b], B = smem[2+b]
        const unsigned short* Ab = &smem[b][0][0];
        const unsigned short* Bb = &smem[2 + b][0][0];
        bf8 af[4], bff[4];
#pragma unroll
        for (int f = 0; f < 4; ++f) {
            af[f]  = *(const bf8*)(Ab + (wr * 64 + f * 16 + (lane & 15)) * 32 + (lane >> 4) * 8);
            bff[f] = *(const bf8*)(Bb + (wc * 64 + f * 16 + (lane & 15)) * 32 + (lane >> 4) * 8);
        }
#pragma unroll
        for (int i = 0; i < 4; ++i)
#pragma unroll
            for (int j = 0; j < 4; ++j)
                acc[i][j] = __builtin_amdgcn_mfma_f32_16x16x32_bf16(af[i], bff[j],
                                                                    acc[i][j], 0, 0, 0);
    };

    for (int k0 = 0; k0 < K; k0 += 64) {
        float4 f0a = *(const float4*)(fA0 + k0);      float4 f0b = *(const float4*)(fA0 + k0 + 4);
        float4 f1a = *(const float4*)(fA1 + k0);      float4 f1b = *(const float4*)(fA1 + k0 + 4);
        float4 f0c = *(const float4*)(fA0 + k0 + 32); float4 f0d = *(const float4*)(fA0 + k0 + 36);
        float4 f1c = *(const float4*)(fA1 + k0 + 32); float4 f1d = *(const float4*)(fA1 + k0 + 36);
        __syncthreads();
        *(uint4*)(&smem[0][0][0] + tid * 8)  = pack8(f0a, f0b);
        *(uint4*)(&smem[0][64][0] + tid * 8) = pack8(f1a, f1b);
        *(uint4*)(&smem[1][0][0] + tid * 8)  = pack8(f0c, f0d);
        *(uint4*)(&smem[1][64][0] + tid * 8) = pack8(f1c, f1d);
        gload16(gB0 + k0,      &smem[2][0][0] + tid * 8);
        gload16(gB1 + k0,      &smem[2][64][0] + tid * 8);
        gload16(gB0 + k0 + 32, &smem[3][0][0] + tid * 8);
        gload16(gB1 + k0 + 32, &smem[3][64][0] + tid * 8);
        __syncthreads();
        compute(0);
        compute(1);
    }

#pragma unroll
    for (int i = 0; i < 4; ++i) {
        int rb = m0 + wr * 64 + i * 16 + (lane >> 4) * 4;
#pragma unroll
        for (int j = 0; j < 4; ++j) {
            int cc = n0 + wc * 64 + j * 16 + (lane & 15);
#pragma unroll
            for (int e = 0; e < 4; ++e) {
                int r = rb + e;
                if (r < M) CF[(size_t)r * EMB + cc] = f2bf(acc[i][j][e]);
            }
        }
    }
}

// ---------------------------------------------------------------------------
// LN body: LN(bf16 X + fp32 bias) + act -> bf16.
// ---------------------------------------------------------------------------
template <int ACT>
__device__ __forceinline__ void ln_body(const unsigned short* X,
                                        const float* bias, const float* g,
                                        const float* b, unsigned short* Y, int row) {
    __shared__ float red[8];
    int t = threadIdx.x;
    unsigned v = *(const unsigned*)(X + (size_t)row * EMB + 2 * t);
    float x0 = bflo(v) + bias[2 * t];
    float x1 = bfhi(v) + bias[2 * t + 1];
    float s = x0 + x1;
    float q = x0 * x0 + x1 * x1;
#pragma unroll
    for (int off = 32; off > 0; off >>= 1) {
        s += __shfl_down(s, off);
        q += __shfl_down(q, off);
    }
    int wave = t >> 6, lane = t & 63;
    if (lane == 0) { red[wave * 2] = s; red[wave * 2 + 1] = q; }
    __syncthreads();
    if (t == 0) {
        float ts = 0.f, tq = 0.f;
        for (int w = 0; w < 4; w++) { ts += red[w * 2]; tq += red[w * 2 + 1]; }
        red[0] = ts; red[1] = tq;
    }
    __syncthreads();
    float mu   = red[0] * (1.0f / 512.0f);
    float var  = red[1] * (1.0f / 512.0f) - mu * mu;
    float rstd = rsqrtf(var + LN_EPS);
    float y0 = (x0 - mu) * rstd * g[2 * t]     + b[2 * t];
    float y1 = (x1 - mu) * rstd * g[2 * t + 1] + b[2 * t + 1];
    if (ACT == 0) {  // exact GELU
        y0 = 0.5f * y0 * (1.0f + erff(y0 * 0.70710678118654752440f));
        y1 = 0.5f * y1 * (1.0f + erff(y1 * 0.70710678118654752440f));
    } else {         // SiLU
        y0 = y0 / (1.0f + expf(-y0));
        y1 = y1 / (1.0f + expf(-y1));
    }
    ((unsigned*)Y)[(size_t)row * (EMB / 2) + t] = packbf(y0, y1);
}

template <int ACT>
__global__ __launch_bounds__(256) void k_ln_b(const unsigned short* __restrict__ X,
                                              const float* __restrict__ bias,
                                              const float* __restrict__ g,
                                              const float* __restrict__ b,
                                              unsigned short* __restrict__ Y) {
    ln_body<ACT>(X, bias, g, b, Y, blockIdx.x);
}

// ---------------------------------------------------------------------------
// MERGED: sliced sage1 (C0,C1 -> Pd) + LN<0> (F0 -> actA).
// grid (8, 3125): y < 625 -> sage(slice=x, nblk=y);
// y >= 625 -> LN row (y-625)*8 + x  (covers 0..19999).
// ---------------------------------------------------------------------------
__global__ __launch_bounds__(256) void k_sageln(const unsigned short* __restrict__ C0,
                                                const unsigned short* __restrict__ C1,
                                                const float* __restrict__ bl1,
                                                const int* __restrict__ row_ptr,
                                                const int* __restrict__ csr,
                                                unsigned short* __restrict__ Pd,
                                                const unsigned short* __restrict__ F0,
                                                const float* __restrict__ bf_,
                                                const float* __restrict__ g1,
                                                const float* __restrict__ b1,
                                                unsigned short* __restrict__ fout) {
    __shared__ int sIdx[IDX_CAP];
    if (blockIdx.y < 625) {
        sage_body<0>(C0, C1, bl1, row_ptr, csr, Pd, blockIdx.x, blockIdx.y, sIdx);
    } else {
        ln_body<0>(F0, bf_, g1, b1, fout, (blockIdx.y - 625) * 8 + blockIdx.x);
    }
}

// ---------------------------------------------------------------------------
extern "C" void kernel_launch(void* const* d_in, const int* in_sizes, int n_in,
                              void* d_out, int out_size, void* d_ws, size_t ws_size,
                              hipStream_t stream) {
    const float* x_found = (const float*)d_in[0];
    const float* x_exp   = (const float*)d_in[1];
    const int*   ppi     = (const int*)d_in[2];
    const float* Wl0 = (const float*)d_in[3];
    const float* bl0 = (const float*)d_in[4];
    const float* Wr0 = (const float*)d_in[5];
    const float* Wl1 = (const float*)d_in[6];
    const float* bl1 = (const float*)d_in[7];
    const float* Wr1 = (const float*)d_in[8];
    const float* Wf  = (const float*)d_in[9];
    const float* bf_ = (const float*)d_in[10];
    const float* g1  = (const float*)d_in[11];
    const float* b1  = (const float*)d_in[12];
    const float* Wfu = (const float*)d_in[13];
    const float* bfu = (const float*)d_in[14];
    const float* g2  = (const float*)d_in[15];
    const float* b2  = (const float*)d_in[16];
    const float* Wl2 = (const float*)d_in[17];
    const float* bl2 = (const float*)d_in[18];
    const float* Wr2 = (const float*)d_in[19];

    const int* e_src = ppi;
    const int* e_dst = ppi + N_EDGES;

    char* ws = (char*)d_ws;
    unsigned short* C0   = (unsigned short*)(ws);                 // 20,480,000 B
    unsigned short* C1   = (unsigned short*)(ws + 20480000);      // 20,480,000 B
    unsigned short* actA = (unsigned short*)(ws + 40960000);      // 20,480,000 B
    int* cnt     = (int*)(ws + 61440000);   // 80,000 B
    int* row_ptr = (int*)(ws + 61520000);   // 80,004 B (padded)
    unsigned char* eslot = (unsigned char*)(ws + 61600064);  // 640,000 B
    int* csr     = (int*)(ws + 62240064);   // 2,560,000 B -> 64,800,064
    unsigned short* Wb = (unsigned short*)(ws + 64800064);        // 5,242,880 B
    unsigned short* Wl0b = Wb;
    unsigned short* Wr0b = Wb + 524288;
    unsigned short* Wl1b = Wb + 1048576;
    unsigned short* Wr1b = Wb + 1310720;
    unsigned short* Wfb  = Wb + 1572864;
    unsigned short* Wfub = Wb + 1835008;
    unsigned short* Wl2b = Wb + 2097152;
    unsigned short* Wr2b = Wb + 2359296;
    int* bsum = (int*)(ws + 70042944);      // 320 B
    int* boff = (int*)(ws + 70043264);      // 324 B -> end ~70.1 MB

    unsigned short* Xe = (unsigned short*)d_out;             // full d_out (until L0 done)
    unsigned short* Pd = (unsigned short*)d_out;             // h2 scratch (lower half)
    unsigned short* F0 = (unsigned short*)d_out + 10240000;  // Wf out (upper half)

    // ---- fused cvt (x_exp + weights) + edge count+slot; then scan
    hipMemsetAsync(cnt, 0, N_GENES * sizeof(int), stream);
    k_cvtcnt<<<4548, 256, 0, stream>>>((const float4*)x_exp,
                                       (const float4*)Wl0, (const float4*)Wr0,
                                       (const float4*)Wl1, (const float4*)Wr1,
                                       (const float4*)Wf,  (const float4*)Wfu,
                                       (const float4*)Wl2, (const float4*)Wr2,
                                       (uint4*)Xe, (uint4*)Wb, e_dst, cnt, eslot);
    k_scan1<<<SCAN_B, 256, 0, stream>>>(cnt, row_ptr, bsum);
    k_scan2<<<1, 128, 0, stream>>>(bsum, boff);
    k_scan3<<<SCAN_B, 256, 0, stream>>>(row_ptr, boff);

    dim3 gg(8, 80);    // fused-add GEMM
    dim3 gp(8, 160);   // pair GEMM
    dim3 gpf(8, 473);  // L0 pair GEMM + atomic-free CSR fill
    dim3 gs(8, 625);   // XCD-sliced sage
    dim3 gsw(8, 705);  // XCD-sliced sage + Wf GEMM merge
    dim3 gsl(8, 3125); // XCD-sliced sage + LN merge

    // ---- layer 0 (K=1024) fused with atomic-free CSR fill
    k_gemm_pf<<<gpf, 256, 0, stream>>>(Xe, Wl0b, Wr0b, C0, C1, N_GENES, N_CELLS,
                                       e_src, e_dst, row_ptr, eslot, csr);
    // ---- merged: sage0 -> actA (h1)  +  foundation GEMM (x_found@Wf -> F0).
    // Xe dead once pf completes; F0 overwrites d_out upper half safely here.
    k_sagewf<<<gsw, 256, 0, stream>>>(C0, C1, bl0, row_ptr, csr, actA,
                                      x_found, Wfb, F0, N_GENES);

    // ---- L1 pair (A=actA) -> C0,C1
    k_gemm_p<<<gp, 256, 0, stream>>>(actA, Wl1b, Wr1b, C0, C1, N_GENES, EMB);
    // ---- merged: sliced sage1 -> Pd  +  LN<0>(F0) -> actA (f)
    k_sageln<<<gsl, 256, 0, stream>>>(C0, C1, bl1, row_ptr, csr,
                                      Pd, F0, bf_, g1, b1, actA);

    // ---- fusion (fused add inside GEMM): fo = SiLU(LN((h2 + f) @ Wfu^T + bfu))
    k_gemm_fu<<<gg, 256, 0, stream>>>(Pd, actA, Wfub, C0, N_GENES, EMB);
    k_ln_b<1><<<N_GENES, 256, 0, stream>>>(C0, bfu, g2, b2, actA);                 // fo

    // ---- final SAGE -> d_out (fp32; Pd and F0 both dead)
    k_gemm_p<<<gp, 256, 0, stream>>>(actA, Wl2b, Wr2b, C0, C1, N_GENES, EMB);
    k_sage_b<1><<<gs, 256, 0, stream>>>(C0, C1, bl2, row_ptr, csr, (float*)d_out);
}

// Round 10
// 431.306 us; speedup vs baseline: 1.0401x; 1.0401x over previous
//
#include <hip/hip_runtime.h>
#include <hip/hip_bf16.h>
#include <math.h>

#define N_GENES 20000
#define N_CELLS 1024
#define FM_DIM  512
#define EMB     512
#define N_EDGES 640000
#define LN_EPS  1e-5f
#define SCAN_B  79   // ceil(20000/256)
#define IDX_CAP 2560 // LDS index-stage capacity (avg block load = 1024)

typedef __attribute__((ext_vector_type(8))) short bf8;
typedef __attribute__((ext_vector_type(4))) float f32x4;

__device__ __forceinline__ float bflo(unsigned v) { return __uint_as_float(v << 16); }
__device__ __forceinline__ float bfhi(unsigned v) { return __uint_as_float(v & 0xffff0000u); }
__device__ __forceinline__ unsigned short f2bf(float f) {
    unsigned u = __float_as_uint(f);
    return (unsigned short)((u + 0x7fffu + ((u >> 16) & 1u)) >> 16);  // RNE
}
__device__ __forceinline__ unsigned packbf(float x, float y) {
    return (unsigned)f2bf(x) | ((unsigned)f2bf(y) << 16);
}
__device__ __forceinline__ unsigned addbf2(unsigned x, unsigned y) {
    return packbf(bflo(x) + bflo(y), bfhi(x) + bfhi(y));
}
__device__ __forceinline__ uint4 pack8(float4 a, float4 b) {
    uint4 o;
    o.x = packbf(a.x, a.y);
    o.y = packbf(a.z, a.w);
    o.z = packbf(b.x, b.y);
    o.w = packbf(b.z, b.w);
    return o;
}

// async global->LDS, 16 B per lane. LDS dest must be wave-uniform base + lane*16.
__device__ __forceinline__ void gload16(const unsigned short* g, unsigned short* l) {
    __builtin_amdgcn_global_load_lds(
        (const __attribute__((address_space(1))) unsigned int*)g,
        (__attribute__((address_space(3))) unsigned int*)l, 16, 0, 0);
}

// ---------------------------------------------------------------------------
// Fused: x_exp cvt (grid-stride) + 8-weight cvt + edge count+slot, one launch.
// ---------------------------------------------------------------------------
__global__ __launch_bounds__(256) void k_cvtcnt(const float4* __restrict__ xe,
                                                const float4* s0, const float4* s1,
                                                const float4* s2, const float4* s3,
                                                const float4* s4, const float4* s5,
                                                const float4* s6, const float4* s7,
                                                uint4* __restrict__ Xe,
                                                uint4* __restrict__ Wb,
                                                const int* __restrict__ edst,
                                                int* __restrict__ cnt,
                                                unsigned char* __restrict__ eslot) {
    if (blockIdx.x < 2048) {
        for (int i = blockIdx.x * 256 + threadIdx.x; i < 2560000 + 327680;
             i += 2048 * 256) {
            if (i < 2560000) {
                Xe[i] = pack8(xe[2 * i], xe[2 * i + 1]);
            } else {
                int w = i - 2560000;
                const float4* src; int off;
                if (w < 65536)       { src = s0; off = w; }
                else if (w < 131072) { src = s1; off = w - 65536; }
                else if (w < 163840) { src = s2; off = w - 131072; }
                else if (w < 196608) { src = s3; off = w - 163840; }
                else if (w < 229376) { src = s4; off = w - 196608; }
                else if (w < 262144) { src = s5; off = w - 229376; }
                else if (w < 294912) { src = s6; off = w - 262144; }
                else                 { src = s7; off = w - 294912; }
                Wb[w] = pack8(src[2 * off], src[2 * off + 1]);
            }
        }
    } else {
        int e = (blockIdx.x - 2048) * 256 + threadIdx.x;
        if (e < N_EDGES) {
            int old = atomicAdd(&cnt[edst[e]], 1);
            eslot[e] = (unsigned char)old;   // max degree ~Poisson(32) << 256
        }
    }
}

// ---------------------------------------------------------------------------
// CSR: hierarchical scan (byte-identical to r15-r19)
// ---------------------------------------------------------------------------
__global__ __launch_bounds__(256) void k_scan1(const int* __restrict__ cnt,
                                               int* __restrict__ row_ptr,
                                               int* __restrict__ bsum) {
    __shared__ int wsum[4];
    int b = blockIdx.x, t = threadIdx.x;
    int i = b * 256 + t;
    int v = (i < N_GENES) ? cnt[i] : 0;
    int lane = t & 63, wv = t >> 6;
    int x = v;
#pragma unroll
    for (int off = 1; off < 64; off <<= 1) {
        int y = __shfl_up(x, off);
        if (lane >= off) x += y;
    }
    if (lane == 63) wsum[wv] = x;
    __syncthreads();
    if (t == 0) {
        int s = 0;
        for (int w = 0; w < 4; ++w) { int tmp = wsum[w]; wsum[w] = s; s += tmp; }
    }
    __syncthreads();
    int excl = x - v + wsum[wv];
    if (i < N_GENES) row_ptr[i] = excl;
    if (t == 255) bsum[b] = excl + v;
}

__global__ void k_scan2(const int* __restrict__ bsum, int* __restrict__ boff) {
    __shared__ int wsum[2];
    int t = threadIdx.x;                      // 128
    int v = (t < SCAN_B) ? bsum[t] : 0;
    int lane = t & 63, wv = t >> 6;
    int x = v;
#pragma unroll
    for (int off = 1; off < 64; off <<= 1) {
        int y = __shfl_up(x, off);
        if (lane >= off) x += y;
    }
    if (lane == 63) wsum[wv] = x;
    __syncthreads();
    int add = (wv == 1) ? wsum[0] : 0;
    int excl = x - v + add;
    if (t < SCAN_B) boff[t] = excl;
    if (t == SCAN_B) boff[SCAN_B] = excl;
}

__global__ __launch_bounds__(256) void k_scan3(int* __restrict__ row_ptr,
                                               const int* __restrict__ boff) {
    int i = blockIdx.x * 256 + threadIdx.x;
    if (i < N_GENES) row_ptr[i] += boff[i >> 8];
    if (blockIdx.x == 0 && threadIdx.x == 0) row_ptr[N_GENES] = boff[SCAN_B];
}

// ---------------------------------------------------------------------------
// L0 PAIR GEMM + ATOMIC-FREE CSR-FILL in one dispatch. grid (8, 473).
// v7: 3-deep pipelined LDS (48 KB) + counted vmcnt(8) (best measured, R7).
// ---------------------------------------------------------------------------
__global__ __launch_bounds__(256) void k_gemm_pf(const unsigned short* __restrict__ A,
                                                 const unsigned short* __restrict__ Wl,
                                                 const unsigned short* __restrict__ Wr,
                                                 unsigned short* __restrict__ C0,
                                                 unsigned short* __restrict__ C1,
                                                 int M, int K,
                                                 const int* __restrict__ e_src,
                                                 const int* __restrict__ e_dst,
                                                 const int* __restrict__ row_ptr,
                                                 const unsigned char* __restrict__ eslot,
                                                 int* __restrict__ csr) {
    __shared__ __attribute__((aligned(16))) unsigned short As[3][128][32];
    __shared__ __attribute__((aligned(16))) unsigned short Bs[3][128][32];
    if (blockIdx.y >= 160) {   // fill path: no atomics, no barriers
        int e = ((blockIdx.y - 160) * 8 + blockIdx.x) * 256 + threadIdx.x;
        if (e < N_EDGES) {
            int d = e_dst[e];
            csr[row_ptr[d] + (int)eslot[e]] = e_src[e];
        }
        return;
    }
    int m0 = (blockIdx.x * 20 + (blockIdx.y >> 3)) * 128;
    if (m0 >= M) return;
    int sel = blockIdx.y & 7;
    const unsigned short* W = (sel < 4) ? Wl : Wr;
    unsigned short* Cp = (sel < 4) ? C0 : C1;
    int n0 = (sel & 3) * 128;
    int tid = threadIdx.x;
    int lane = tid & 63;
    int w = tid >> 6, wr = w >> 1, wc = w & 1;

    int srow = tid >> 2, sch = tid & 3;
    int rA0 = min(m0 + srow, M - 1);
    int rA1 = min(m0 + srow + 64, M - 1);
    const unsigned short* gA0 = A + (size_t)rA0 * K + sch * 8;
    const unsigned short* gA1 = A + (size_t)rA1 * K + sch * 8;
    const unsigned short* gB0 = W + (size_t)(n0 + srow) * K + sch * 8;
    const unsigned short* gB1 = W + (size_t)(n0 + srow + 64) * K + sch * 8;

    f32x4 acc[4][4];
#pragma unroll
    for (int i = 0; i < 4; ++i)
#pragma unroll
        for (int j = 0; j < 4; ++j) acc[i][j] = (f32x4){0.f, 0.f, 0.f, 0.f};

    auto stage = [&](int b, int k0) {   // literal b only -> static after inline
        unsigned short* Ab = &As[b][0][0];
        unsigned short* Bb = &Bs[b][0][0];
        gload16(gA0 + k0, Ab + tid * 8);
        gload16(gA1 + k0, Ab + 64 * 32 + tid * 8);
        gload16(gB0 + k0, Bb + tid * 8);
        gload16(gB1 + k0, Bb + 64 * 32 + tid * 8);
    };
    auto compute = [&](int b) {
        const unsigned short* Ab = &As[b][0][0];
        const unsigned short* Bb = &Bs[b][0][0];
        bf8 af[4], bff[4];
#pragma unroll
        for (int f = 0; f < 4; ++f) {
            af[f]  = *(const bf8*)(Ab + (wr * 64 + f * 16 + (lane & 15)) * 32 + (lane >> 4) * 8);
            bff[f] = *(const bf8*)(Bb + (wc * 64 + f * 16 + (lane & 15)) * 32 + (lane >> 4) * 8);
        }
#pragma unroll
        for (int i = 0; i < 4; ++i)
#pragma unroll
            for (int j = 0; j < 4; ++j)
                acc[i][j] = __builtin_amdgcn_mfma_f32_16x16x32_bf16(af[i], bff[j],
                                                                    acc[i][j], 0, 0, 0);
    };

#define PF_STEP(CB, SB, ST, VM)                                  \
    stage(SB, (ST) * 32);                                        \
    asm volatile("s_waitcnt vmcnt(" #VM ")" ::: "memory");       \
    __builtin_amdgcn_s_barrier();                                \
    __builtin_amdgcn_sched_barrier(0);                           \
    compute(CB);                                                 \
    asm volatile("s_waitcnt lgkmcnt(0)" ::: "memory");           \
    __builtin_amdgcn_s_barrier();                                \
    __builtin_amdgcn_sched_barrier(0);

    const int NT = K / 32;   // 32 for K=1024; main loop assumes NT % 3 == 2
    stage(0, 0);
    stage(1, 32);
    for (int t = 0; t + 4 < NT; t += 3) {
        PF_STEP(0, 2, t + 2, 8)
        PF_STEP(1, 0, t + 3, 8)
        PF_STEP(2, 1, t + 4, 8)
    }
    // peel: tiles NT-2 (buf 0), NT-1 (buf 1); no more staging
    asm volatile("s_waitcnt vmcnt(4)" ::: "memory");
    __builtin_amdgcn_s_barrier();
    __builtin_amdgcn_sched_barrier(0);
    compute(0);
    asm volatile("s_waitcnt lgkmcnt(0)" ::: "memory");
    __builtin_amdgcn_s_barrier();
    __builtin_amdgcn_sched_barrier(0);
    asm volatile("s_waitcnt vmcnt(0)" ::: "memory");
    __builtin_amdgcn_s_barrier();
    __builtin_amdgcn_sched_barrier(0);
    compute(1);
#undef PF_STEP

#pragma unroll
    for (int i = 0; i < 4; ++i) {
        int rb = m0 + wr * 64 + i * 16 + (lane >> 4) * 4;
#pragma unroll
        for (int j = 0; j < 4; ++j) {
            int cc = n0 + wc * 64 + j * 16 + (lane & 15);
#pragma unroll
            for (int e = 0; e < 4; ++e) {
                int r = rb + e;
                if (r < M) Cp[(size_t)r * EMB + cc] = f2bf(acc[i][j][e]);
            }
        }
    }
}

// ---------------------------------------------------------------------------
// FUSED-ADD GEMM, XCD-partitioned: grid (8, 80). BK=64 single-buffer (R6).
// ---------------------------------------------------------------------------
__global__ __launch_bounds__(256) void k_gemm_fu(const unsigned short* __restrict__ A,
                                                 const unsigned short* __restrict__ A2,
                                                 const unsigned short* __restrict__ W,
                                                 unsigned short* __restrict__ Cp,
                                                 int M, int K) {
    __shared__ __attribute__((aligned(16))) unsigned short As[2][128][32];
    __shared__ __attribute__((aligned(16))) unsigned short Bs[2][128][32];
    int m0 = (blockIdx.x * 20 + (blockIdx.y >> 2)) * 128;
    if (m0 >= M) return;
    int n0 = (blockIdx.y & 3) * 128;
    int tid = threadIdx.x;
    int lane = tid & 63;
    int w = tid >> 6, wr = w >> 1, wc = w & 1;

    int srow = tid >> 2, sch = tid & 3;
    int rA0 = min(m0 + srow, M - 1);
    int rA1 = min(m0 + srow + 64, M - 1);
    const unsigned short* gA0 = A + (size_t)rA0 * K + sch * 8;
    const unsigned short* gA1 = A + (size_t)rA1 * K + sch * 8;
    const unsigned short* hA0 = A2 + (size_t)rA0 * K + sch * 8;
    const unsigned short* hA1 = A2 + (size_t)rA1 * K + sch * 8;
    const unsigned short* gB0 = W + (size_t)(n0 + srow) * K + sch * 8;
    const unsigned short* gB1 = W + (size_t)(n0 + srow + 64) * K + sch * 8;

    f32x4 acc[4][4];
#pragma unroll
    for (int i = 0; i < 4; ++i)
#pragma unroll
        for (int j = 0; j < 4; ++j) acc[i][j] = (f32x4){0.f, 0.f, 0.f, 0.f};

    auto compute = [&](int b) {
        const unsigned short* Ab = &As[b][0][0];
        const unsigned short* Bb = &Bs[b][0][0];
        bf8 af[4], bff[4];
#pragma unroll
        for (int f = 0; f < 4; ++f) {
            af[f]  = *(const bf8*)(Ab + (wr * 64 + f * 16 + (lane & 15)) * 32 + (lane >> 4) * 8);
            bff[f] = *(const bf8*)(Bb + (wc * 64 + f * 16 + (lane & 15)) * 32 + (lane >> 4) * 8);
        }
#pragma unroll
        for (int i = 0; i < 4; ++i)
#pragma unroll
            for (int j = 0; j < 4; ++j)
                acc[i][j] = __builtin_amdgcn_mfma_f32_16x16x32_bf16(af[i], bff[j],
                                                                    acc[i][j], 0, 0, 0);
    };

    for (int k0 = 0; k0 < K; k0 += 64) {
        uint4 x00 = *(const uint4*)(gA0 + k0);
        uint4 y00 = *(const uint4*)(hA0 + k0);
        uint4 x10 = *(const uint4*)(gA1 + k0);
        uint4 y10 = *(const uint4*)(hA1 + k0);
        uint4 x01 = *(const uint4*)(gA0 + k0 + 32);
        uint4 y01 = *(const uint4*)(hA0 + k0 + 32);
        uint4 x11 = *(const uint4*)(gA1 + k0 + 32);
        uint4 y11 = *(const uint4*)(hA1 + k0 + 32);
        uint4 a00, a10, a01, a11;
        a00.x = addbf2(x00.x, y00.x); a00.y = addbf2(x00.y, y00.y);
        a00.z = addbf2(x00.z, y00.z); a00.w = addbf2(x00.w, y00.w);
        a10.x = addbf2(x10.x, y10.x); a10.y = addbf2(x10.y, y10.y);
        a10.z = addbf2(x10.z, y10.z); a10.w = addbf2(x10.w, y10.w);
        a01.x = addbf2(x01.x, y01.x); a01.y = addbf2(x01.y, y01.y);
        a01.z = addbf2(x01.z, y01.z); a01.w = addbf2(x01.w, y01.w);
        a11.x = addbf2(x11.x, y11.x); a11.y = addbf2(x11.y, y11.y);
        a11.z = addbf2(x11.z, y11.z); a11.w = addbf2(x11.w, y11.w);
        __syncthreads();
        *(uint4*)(&As[0][0][0] + tid * 8)       = a00;
        *(uint4*)(&As[0][64][0] + tid * 8)      = a10;
        *(uint4*)(&As[1][0][0] + tid * 8)       = a01;
        *(uint4*)(&As[1][64][0] + tid * 8)      = a11;
        gload16(gB0 + k0,      &Bs[0][0][0] + tid * 8);
        gload16(gB1 + k0,      &Bs[0][64][0] + tid * 8);
        gload16(gB0 + k0 + 32, &Bs[1][0][0] + tid * 8);
        gload16(gB1 + k0 + 32, &Bs[1][64][0] + tid * 8);
        __syncthreads();
        compute(0);
        compute(1);
    }

#pragma unroll
    for (int i = 0; i < 4; ++i) {
        int rb = m0 + wr * 64 + i * 16 + (lane >> 4) * 4;
#pragma unroll
        for (int j = 0; j < 4; ++j) {
            int cc = n0 + wc * 64 + j * 16 + (lane & 15);
#pragma unroll
            for (int e = 0; e < 4; ++e) {
                int r = rb + e;
                if (r < M) Cp[(size_t)r * EMB + cc] = f2bf(acc[i][j][e]);
            }
        }
    }
}

// ---------------------------------------------------------------------------
// PAIR GEMM, XCD-partitioned: grid (8, 160). BK=64 single-buffer (R6).
// ---------------------------------------------------------------------------
__global__ __launch_bounds__(256) void k_gemm_p(const unsigned short* __restrict__ A,
                                                const unsigned short* __restrict__ Wl,
                                                const unsigned short* __restrict__ Wr,
                                                unsigned short* __restrict__ C0,
                                                unsigned short* __restrict__ C1,
                                                int M, int K) {
    __shared__ __attribute__((aligned(16))) unsigned short As[2][128][32];
    __shared__ __attribute__((aligned(16))) unsigned short Bs[2][128][32];
    int m0 = (blockIdx.x * 20 + (blockIdx.y >> 3)) * 128;
    if (m0 >= M) return;
    int sel = blockIdx.y & 7;
    const unsigned short* W = (sel < 4) ? Wl : Wr;
    unsigned short* Cp = (sel < 4) ? C0 : C1;
    int n0 = (sel & 3) * 128;
    int tid = threadIdx.x;
    int lane = tid & 63;
    int w = tid >> 6, wr = w >> 1, wc = w & 1;

    int srow = tid >> 2, sch = tid & 3;
    int rA0 = min(m0 + srow, M - 1);
    int rA1 = min(m0 + srow + 64, M - 1);
    const unsigned short* gA0 = A + (size_t)rA0 * K + sch * 8;
    const unsigned short* gA1 = A + (size_t)rA1 * K + sch * 8;
    const unsigned short* gB0 = W + (size_t)(n0 + srow) * K + sch * 8;
    const unsigned short* gB1 = W + (size_t)(n0 + srow + 64) * K + sch * 8;

    f32x4 acc[4][4];
#pragma unroll
    for (int i = 0; i < 4; ++i)
#pragma unroll
        for (int j = 0; j < 4; ++j) acc[i][j] = (f32x4){0.f, 0.f, 0.f, 0.f};

    auto compute = [&](int b) {
        const unsigned short* Ab = &As[b][0][0];
        const unsigned short* Bb = &Bs[b][0][0];
        bf8 af[4], bff[4];
#pragma unroll
        for (int f = 0; f < 4; ++f) {
            af[f]  = *(const bf8*)(Ab + (wr * 64 + f * 16 + (lane & 15)) * 32 + (lane >> 4) * 8);
            bff[f] = *(const bf8*)(Bb + (wc * 64 + f * 16 + (lane & 15)) * 32 + (lane >> 4) * 8);
        }
#pragma unroll
        for (int i = 0; i < 4; ++i)
#pragma unroll
            for (int j = 0; j < 4; ++j)
                acc[i][j] = __builtin_amdgcn_mfma_f32_16x16x32_bf16(af[i], bff[j],
                                                                    acc[i][j], 0, 0, 0);
    };

    for (int k0 = 0; k0 < K; k0 += 64) {
        __syncthreads();
        gload16(gA0 + k0,      &As[0][0][0] + tid * 8);
        gload16(gA1 + k0,      &As[0][64][0] + tid * 8);
        gload16(gA0 + k0 + 32, &As[1][0][0] + tid * 8);
        gload16(gA1 + k0 + 32, &As[1][64][0] + tid * 8);
        gload16(gB0 + k0,      &Bs[0][0][0] + tid * 8);
        gload16(gB1 + k0,      &Bs[0][64][0] + tid * 8);
        gload16(gB0 + k0 + 32, &Bs[1][0][0] + tid * 8);
        gload16(gB1 + k0 + 32, &Bs[1][64][0] + tid * 8);
        __syncthreads();
        compute(0);
        compute(1);
    }

#pragma unroll
    for (int i = 0; i < 4; ++i) {
        int rb = m0 + wr * 64 + i * 16 + (lane >> 4) * 4;
#pragma unroll
        for (int j = 0; j < 4; ++j) {
            int cc = n0 + wc * 64 + j * 16 + (lane & 15);
#pragma unroll
            for (int e = 0; e < 4; ++e) {
                int r = rb + e;
                if (r < M) Cp[(size_t)r * EMB + cc] = f2bf(acc[i][j][e]);
            }
        }
    }
}

// ---------------------------------------------------------------------------
// TRIPLE GEMM: L1 pair (A1 bf16, gload_lds) + Wf single (A2 fp32, reg-staged),
// grid (8, 240). BK=64 single-buffer (R6); B always via gload_lds.
// ---------------------------------------------------------------------------
__global__ __launch_bounds__(256) void k_gemm_3(const unsigned short* __restrict__ A1,
                                                const float* __restrict__ A2,
                                                const unsigned short* __restrict__ Wl,
                                                const unsigned short* __restrict__ Wr,
                                                const unsigned short* __restrict__ Wf,
                                                unsigned short* __restrict__ C0,
                                                unsigned short* __restrict__ C1,
                                                unsigned short* __restrict__ CF,
                                                int M) {
    const int K = 512;
    __shared__ __attribute__((aligned(16))) unsigned short As[2][128][32];
    __shared__ __attribute__((aligned(16))) unsigned short Bs[2][128][32];
    int y = blockIdx.y;
    bool fpath = (y >= 160);
    int m0, n0;
    const unsigned short* W;
    unsigned short* Cp;
    if (!fpath) {
        m0 = (blockIdx.x * 20 + (y >> 3)) * 128;
        int sel = y & 7;
        W = (sel < 4) ? Wl : Wr;
        Cp = (sel < 4) ? C0 : C1;
        n0 = (sel & 3) * 128;
    } else {
        int y2 = y - 160;
        m0 = (blockIdx.x * 20 + (y2 >> 2)) * 128;
        n0 = (y2 & 3) * 128;
        W = Wf;
        Cp = CF;
    }
    if (m0 >= M) return;
    int tid = threadIdx.x;
    int lane = tid & 63;
    int w = tid >> 6, wr = w >> 1, wc = w & 1;

    int srow = tid >> 2, sch = tid & 3;
    int rA0 = min(m0 + srow, M - 1);
    int rA1 = min(m0 + srow + 64, M - 1);
    const unsigned short* gA0 = A1 + (size_t)rA0 * K + sch * 8;
    const unsigned short* gA1 = A1 + (size_t)rA1 * K + sch * 8;
    const float* fA0 = A2 + (size_t)rA0 * K + sch * 8;
    const float* fA1 = A2 + (size_t)rA1 * K + sch * 8;
    const unsigned short* gB0 = W + (size_t)(n0 + srow) * K + sch * 8;
    const unsigned short* gB1 = W + (size_t)(n0 + srow + 64) * K + sch * 8;

    f32x4 acc[4][4];
#pragma unroll
    for (int i = 0; i < 4; ++i)
#pragma unroll
        for (int j = 0; j < 4; ++j) acc[i][j] = (f32x4){0.f, 0.f, 0.f, 0.f};

    auto compute = [&](int b) {
        const unsigned short* Ab = &As[b][0][0];
        const unsigned short* Bb = &Bs[b][0][0];
        bf8 af[4], bff[4];
#pragma unroll
        for (int f = 0; f < 4; ++f) {
            af[f]  = *(const bf8*)(Ab + (wr * 64 + f * 16 + (lane & 15)) * 32 + (lane >> 4) * 8);
            bff[f] = *(const bf8*)(Bb + (wc * 64 + f * 16 + (lane & 15)) * 32 + (lane >> 4) * 8);
        }
#pragma unroll
        for (int i = 0; i < 4; ++i)
#pragma unroll
            for (int j = 0; j < 4; ++j)
                acc[i][j] = __builtin_amdgcn_mfma_f32_16x16x32_bf16(af[i], bff[j],
                                                                    acc[i][j], 0, 0, 0);
    };

    for (int k0 = 0; k0 < K; k0 += 64) {
        float4 f0a, f0b, f0c, f0d, f1a, f1b, f1c, f1d;
        if (fpath) {  // block-uniform branch: fp32 loads issued before barrier
            f0a = *(const float4*)(fA0 + k0);      f0b = *(const float4*)(fA0 + k0 + 4);
            f1a = *(const float4*)(fA1 + k0);      f1b = *(const float4*)(fA1 + k0 + 4);
            f0c = *(const float4*)(fA0 + k0 + 32); f0d = *(const float4*)(fA0 + k0 + 36);
            f1c = *(const float4*)(fA1 + k0 + 32); f1d = *(const float4*)(fA1 + k0 + 36);
        }
        __syncthreads();
        if (fpath) {
            *(uint4*)(&As[0][0][0] + tid * 8)  = pack8(f0a, f0b);
            *(uint4*)(&As[0][64][0] + tid * 8) = pack8(f1a, f1b);
            *(uint4*)(&As[1][0][0] + tid * 8)  = pack8(f0c, f0d);
            *(uint4*)(&As[1][64][0] + tid * 8) = pack8(f1c, f1d);
        } else {
            gload16(gA0 + k0,      &As[0][0][0] + tid * 8);
            gload16(gA1 + k0,      &As[0][64][0] + tid * 8);
            gload16(gA0 + k0 + 32, &As[1][0][0] + tid * 8);
            gload16(gA1 + k0 + 32, &As[1][64][0] + tid * 8);
        }
        gload16(gB0 + k0,      &Bs[0][0][0] + tid * 8);
        gload16(gB1 + k0,      &Bs[0][64][0] + tid * 8);
        gload16(gB0 + k0 + 32, &Bs[1][0][0] + tid * 8);
        gload16(gB1 + k0 + 32, &Bs[1][64][0] + tid * 8);
        __syncthreads();
        compute(0);
        compute(1);
    }

#pragma unroll
    for (int i = 0; i < 4; ++i) {
        int rb = m0 + wr * 64 + i * 16 + (lane >> 4) * 4;
#pragma unroll
        for (int j = 0; j < 4; ++j) {
            int cc = n0 + wc * 64 + j * 16 + (lane & 15);
#pragma unroll
            for (int e = 0; e < 4; ++e) {
                int r = rb + e;
                if (r < M) Cp[(size_t)r * EMB + cc] = f2bf(acc[i][j][e]);
            }
        }
    }
}

// ---------------------------------------------------------------------------
// Sage body v3, XCD-SLICED: slice (128 B cols) pinned to XCD via grid x-dim.
// Block = 32 nodes x 8 lanes; lane l covers uint4 word slice*8+l (16 B).
// v3: 16-deep gather batches (256 B/thread in flight, 2x MLP vs v2).
// Accumulation stays one sequential chain per component in CSR order ->
// bitwise-identical to v2.
// ---------------------------------------------------------------------------
template <int OUTF32>
__device__ __forceinline__ void sage_body(const unsigned short* yl,
                                          const unsigned short* yr,
                                          const float* bl,
                                          const int* row_ptr,
                                          const int* csr,
                                          void* outp, int slice, int nblk,
                                          int* sIdx) {
    int g = threadIdx.x >> 3;            // node in block: 0..31
    int l = threadIdx.x & 7;             // lane in group: 0..7
    int node = nblk * 32 + g;
    int w = slice * 8 + l;               // uint4 word index 0..63
    int s32 = row_ptr[nblk * 32];
    int e32 = row_ptr[nblk * 32 + 32];
    int nIdx = e32 - s32;
    bool lds_ok = (nIdx <= IDX_CAP);
    if (lds_ok) {
        for (int i = threadIdx.x; i < nIdx; i += 256) sIdx[i] = csr[s32 + i];
    }
    __syncthreads();
    int s = row_ptr[node], e = row_ptr[node + 1];
    int deg = e - s;
    const char* Yb = (const char*)yl;    // row stride 1024 B
    unsigned lb = (unsigned)(w << 4);
    float ac[8];
#pragma unroll
    for (int q = 0; q < 8; ++q) ac[q] = 0.f;
    if (lds_ok) {
        int lp = s - s32;
        int p = 0;
        for (; p + 16 <= deg; p += 16) {   // 16-deep: 16 loads in flight
            int j[16];
#pragma unroll
            for (int q = 0; q < 16; ++q) j[q] = sIdx[lp + p + q];
            uint4 v[16];
#pragma unroll
            for (int q = 0; q < 16; ++q)
                v[q] = *(const uint4*)(Yb + (((unsigned)j[q] << 10) + lb));
#pragma unroll
            for (int q = 0; q < 16; ++q) {
                ac[0] += bflo(v[q].x); ac[1] += bfhi(v[q].x);
                ac[2] += bflo(v[q].y); ac[3] += bfhi(v[q].y);
                ac[4] += bflo(v[q].z); ac[5] += bfhi(v[q].z);
                ac[6] += bflo(v[q].w); ac[7] += bfhi(v[q].w);
            }
        }
        for (; p + 8 <= deg; p += 8) {
            int j[8];
#pragma unroll
            for (int q = 0; q < 8; ++q) j[q] = sIdx[lp + p + q];
            uint4 v[8];
#pragma unroll
            for (int q = 0; q < 8; ++q)
                v[q] = *(const uint4*)(Yb + (((unsigned)j[q] << 10) + lb));
#pragma unroll
            for (int q = 0; q < 8; ++q) {
                ac[0] += bflo(v[q].x); ac[1] += bfhi(v[q].x);
                ac[2] += bflo(v[q].y); ac[3] += bfhi(v[q].y);
                ac[4] += bflo(v[q].z); ac[5] += bfhi(v[q].z);
                ac[6] += bflo(v[q].w); ac[7] += bfhi(v[q].w);
            }
        }
        for (; p < deg; ++p) {
            int j = sIdx[lp + p];
            uint4 v = *(const uint4*)(Yb + (((unsigned)j << 10) + lb));
            ac[0] += bflo(v.x); ac[1] += bfhi(v.x);
            ac[2] += bflo(v.y); ac[3] += bfhi(v.y);
            ac[4] += bflo(v.z); ac[5] += bfhi(v.z);
            ac[6] += bflo(v.w); ac[7] += bfhi(v.w);
        }
    } else {  // overflow fallback (never expected for this input)
        for (int p = s; p < e; ++p) {
            int j = csr[p];
            uint4 v = *(const uint4*)(Yb + (((unsigned)j << 10) + lb));
            ac[0] += bflo(v.x); ac[1] += bfhi(v.x);
            ac[2] += bflo(v.y); ac[3] += bfhi(v.y);
            ac[4] += bflo(v.z); ac[5] += bfhi(v.z);
            ac[6] += bflo(v.w); ac[7] += bfhi(v.w);
        }
    }
    float inv = 1.f / fmaxf((float)deg, 1.f);
    uint4 vr = ((const uint4*)yr)[(size_t)node * 64 + w];
    float4 bA = ((const float4*)bl)[2 * w];
    float4 bB = ((const float4*)bl)[2 * w + 1];
    float o[8];
    o[0] = ac[0] * inv + bA.x + bflo(vr.x);
    o[1] = ac[1] * inv + bA.y + bfhi(vr.x);
    o[2] = ac[2] * inv + bA.z + bflo(vr.y);
    o[3] = ac[3] * inv + bA.w + bfhi(vr.y);
    o[4] = ac[4] * inv + bB.x + bflo(vr.z);
    o[5] = ac[5] * inv + bB.y + bfhi(vr.z);
    o[6] = ac[6] * inv + bB.z + bflo(vr.w);
    o[7] = ac[7] * inv + bB.w + bfhi(vr.w);
#pragma unroll
    for (int q = 0; q < 8; ++q) o[q] = o[q] > 0.f ? o[q] : expm1f(o[q]);
    if (OUTF32) {
        float4* O = (float4*)outp;
        O[(size_t)node * 128 + 2 * w]     = make_float4(o[0], o[1], o[2], o[3]);
        O[(size_t)node * 128 + 2 * w + 1] = make_float4(o[4], o[5], o[6], o[7]);
    } else {
        uint4 ov;
        ov.x = packbf(o[0], o[1]);
        ov.y = packbf(o[2], o[3]);
        ov.z = packbf(o[4], o[5]);
        ov.w = packbf(o[6], o[7]);
        ((uint4*)outp)[(size_t)node * 64 + w] = ov;
    }
}

// grid (8, 625): x = slice/XCD, y = node block (32 nodes)
template <int OUTF32>
__global__ __launch_bounds__(256) void k_sage_b(const unsigned short* __restrict__ yl,
                                                const unsigned short* __restrict__ yr,
                                                const float* __restrict__ bl,
                                                const int* __restrict__ row_ptr,
                                                const int* __restrict__ csr,
                                                void* __restrict__ outp) {
    __shared__ int sIdx[IDX_CAP];
    sage_body<OUTF32>(yl, yr, bl, row_ptr, csr, outp, blockIdx.x, blockIdx.y, sIdx);
}

// ---------------------------------------------------------------------------
// LN body: LN(bf16 X + fp32 bias) + act -> bf16.
// ---------------------------------------------------------------------------
template <int ACT>
__device__ __forceinline__ void ln_body(const unsigned short* X,
                                        const float* bias, const float* g,
                                        const float* b, unsigned short* Y, int row) {
    __shared__ float red[8];
    int t = threadIdx.x;
    unsigned v = *(const unsigned*)(X + (size_t)row * EMB + 2 * t);
    float x0 = bflo(v) + bias[2 * t];
    float x1 = bfhi(v) + bias[2 * t + 1];
    float s = x0 + x1;
    float q = x0 * x0 + x1 * x1;
#pragma unroll
    for (int off = 32; off > 0; off >>= 1) {
        s += __shfl_down(s, off);
        q += __shfl_down(q, off);
    }
    int wave = t >> 6, lane = t & 63;
    if (lane == 0) { red[wave * 2] = s; red[wave * 2 + 1] = q; }
    __syncthreads();
    if (t == 0) {
        float ts = 0.f, tq = 0.f;
        for (int w = 0; w < 4; w++) { ts += red[w * 2]; tq += red[w * 2 + 1]; }
        red[0] = ts; red[1] = tq;
    }
    __syncthreads();
    float mu   = red[0] * (1.0f / 512.0f);
    float var  = red[1] * (1.0f / 512.0f) - mu * mu;
    float rstd = rsqrtf(var + LN_EPS);
    float y0 = (x0 - mu) * rstd * g[2 * t]     + b[2 * t];
    float y1 = (x1 - mu) * rstd * g[2 * t + 1] + b[2 * t + 1];
    if (ACT == 0) {  // exact GELU
        y0 = 0.5f * y0 * (1.0f + erff(y0 * 0.70710678118654752440f));
        y1 = 0.5f * y1 * (1.0f + erff(y1 * 0.70710678118654752440f));
    } else {         // SiLU
        y0 = y0 / (1.0f + expf(-y0));
        y1 = y1 / (1.0f + expf(-y1));
    }
    ((unsigned*)Y)[(size_t)row * (EMB / 2) + t] = packbf(y0, y1);
}

template <int ACT>
__global__ __launch_bounds__(256) void k_ln_b(const unsigned short* __restrict__ X,
                                              const float* __restrict__ bias,
                                              const float* __restrict__ g,
                                              const float* __restrict__ b,
                                              unsigned short* __restrict__ Y) {
    ln_body<ACT>(X, bias, g, b, Y, blockIdx.x);
}

// ---------------------------------------------------------------------------
// MERGED: sliced sage1 (C0,C1 -> Pd) + LN<0> (F0 -> actA).
// grid (8, 3125): y < 625 -> sage(slice=x, nblk=y);
// y >= 625 -> LN row (y-625)*8 + x  (covers 0..19999).
// ---------------------------------------------------------------------------
__global__ __launch_bounds__(256) void k_sageln(const unsigned short* __restrict__ C0,
                                                const unsigned short* __restrict__ C1,
                                                const float* __restrict__ bl1,
                                                const int* __restrict__ row_ptr,
                                                const int* __restrict__ csr,
                                                unsigned short* __restrict__ Pd,
                                                const unsigned short* __restrict__ F0,
                                                const float* __restrict__ bf_,
                                                const float* __restrict__ g1,
                                                const float* __restrict__ b1,
                                                unsigned short* __restrict__ fout) {
    __shared__ int sIdx[IDX_CAP];
    if (blockIdx.y < 625) {
        sage_body<0>(C0, C1, bl1, row_ptr, csr, Pd, blockIdx.x, blockIdx.y, sIdx);
    } else {
        ln_body<0>(F0, bf_, g1, b1, fout, (blockIdx.y - 625) * 8 + blockIdx.x);
    }
}

// ---------------------------------------------------------------------------
extern "C" void kernel_launch(void* const* d_in, const int* in_sizes, int n_in,
                              void* d_out, int out_size, void* d_ws, size_t ws_size,
                              hipStream_t stream) {
    const float* x_found = (const float*)d_in[0];
    const float* x_exp   = (const float*)d_in[1];
    const int*   ppi     = (const int*)d_in[2];
    const float* Wl0 = (const float*)d_in[3];
    const float* bl0 = (const float*)d_in[4];
    const float* Wr0 = (const float*)d_in[5];
    const float* Wl1 = (const float*)d_in[6];
    const float* bl1 = (const float*)d_in[7];
    const float* Wr1 = (const float*)d_in[8];
    const float* Wf  = (const float*)d_in[9];
    const float* bf_ = (const float*)d_in[10];
    const float* g1  = (const float*)d_in[11];
    const float* b1  = (const float*)d_in[12];
    const float* Wfu = (const float*)d_in[13];
    const float* bfu = (const float*)d_in[14];
    const float* g2  = (const float*)d_in[15];
    const float* b2  = (const float*)d_in[16];
    const float* Wl2 = (const float*)d_in[17];
    const float* bl2 = (const float*)d_in[18];
    const float* Wr2 = (const float*)d_in[19];

    const int* e_src = ppi;
    const int* e_dst = ppi + N_EDGES;

    char* ws = (char*)d_ws;
    unsigned short* C0   = (unsigned short*)(ws);                 // 20,480,000 B
    unsigned short* C1   = (unsigned short*)(ws + 20480000);      // 20,480,000 B
    unsigned short* actA = (unsigned short*)(ws + 40960000);      // 20,480,000 B
    int* cnt     = (int*)(ws + 61440000);   // 80,000 B
    int* row_ptr = (int*)(ws + 61520000);   // 80,004 B (padded)
    unsigned char* eslot = (unsigned char*)(ws + 61600064);  // 640,000 B
    int* csr     = (int*)(ws + 62240064);   // 2,560,000 B -> 64,800,064
    unsigned short* Wb = (unsigned short*)(ws + 64800064);        // 5,242,880 B
    unsigned short* Wl0b = Wb;
    unsigned short* Wr0b = Wb + 524288;
    unsigned short* Wl1b = Wb + 1048576;
    unsigned short* Wr1b = Wb + 1310720;
    unsigned short* Wfb  = Wb + 1572864;
    unsigned short* Wfub = Wb + 1835008;
    unsigned short* Wl2b = Wb + 2097152;
    unsigned short* Wr2b = Wb + 2359296;
    int* bsum = (int*)(ws + 70042944);      // 320 B
    int* boff = (int*)(ws + 70043264);      // 324 B -> end ~70.1 MB

    unsigned short* Xe = (unsigned short*)d_out;             // full d_out (until L0 done)
    unsigned short* Pd = (unsigned short*)d_out;             // h2 scratch (lower half)
    unsigned short* F0 = (unsigned short*)d_out + 10240000;  // Wf out (upper half)

    // ---- fused cvt (x_exp + weights) + edge count+slot; then scan
    hipMemsetAsync(cnt, 0, N_GENES * sizeof(int), stream);
    k_cvtcnt<<<4548, 256, 0, stream>>>((const float4*)x_exp,
                                       (const float4*)Wl0, (const float4*)Wr0,
                                       (const float4*)Wl1, (const float4*)Wr1,
                                       (const float4*)Wf,  (const float4*)Wfu,
                                       (const float4*)Wl2, (const float4*)Wr2,
                                       (uint4*)Xe, (uint4*)Wb, e_dst, cnt, eslot);
    k_scan1<<<SCAN_B, 256, 0, stream>>>(cnt, row_ptr, bsum);
    k_scan2<<<1, 128, 0, stream>>>(bsum, boff);
    k_scan3<<<SCAN_B, 256, 0, stream>>>(row_ptr, boff);

    dim3 gg(8, 80);    // fused-add GEMM
    dim3 gp(8, 160);   // pair GEMM
    dim3 g3(8, 240);   // triple GEMM (pair + Wf)
    dim3 gpf(8, 473);  // L0 pair GEMM + atomic-free CSR fill
    dim3 gs(8, 625);   // XCD-sliced sage
    dim3 gsl(8, 3125); // XCD-sliced sage + LN merge

    // ---- layer 0 (K=1024) fused with atomic-free CSR fill
    k_gemm_pf<<<gpf, 256, 0, stream>>>(Xe, Wl0b, Wr0b, C0, C1, N_GENES, N_CELLS,
                                       e_src, e_dst, row_ptr, eslot, csr);
    k_sage_b<0><<<gs, 256, 0, stream>>>(C0, C1, bl0, row_ptr, csr, actA);          // h1
    // Xe dead from here on.

    // ---- merged: L1 pair (A=actA) + foundation Wf (A=x_found) -> C0,C1,F0
    k_gemm_3<<<g3, 256, 0, stream>>>(actA, x_found, Wl1b, Wr1b, Wfb,
                                     C0, C1, F0, N_GENES);
    // ---- merged: sliced sage1 -> Pd  +  LN<0>(F0) -> actA (f)
    k_sageln<<<gsl, 256, 0, stream>>>(C0, C1, bl1, row_ptr, csr,
                                      Pd, F0, bf_, g1, b1, actA);

    // ---- fusion (fused add inside GEMM): fo = SiLU(LN((h2 + f) @ Wfu^T + bfu))
    k_gemm_fu<<<gg, 256, 0, stream>>>(Pd, actA, Wfub, C0, N_GENES, EMB);
    k_ln_b<1><<<N_GENES, 256, 0, stream>>>(C0, bfu, g2, b2, actA);                 // fo

    // ---- final SAGE -> d_out (fp32; Pd and F0 both dead)
    k_gemm_p<<<gp, 256, 0, stream>>>(actA, Wl2b, Wr2b, C0, C1, N_GENES, EMB);
    k_sage_b<1><<<gs, 256, 0, stream>>>(C0, C1, bl2, row_ptr, csr, (float*)d_out);
}

// Round 11
// 412.647 us; speedup vs baseline: 1.0871x; 1.0452x over previous
//
#include <hip/hip_runtime.h>
#include <hip/hip_bf16.h>
#include <math.h>

#define N_GENES 20000
#define N_CELLS 1024
#define FM_DIM  512
#define EMB     512
#define N_EDGES 640000
#define LN_EPS  1e-5f
#define SCAN_B  79   // ceil(20000/256)
#define IDX_CAP 2560 // LDS index-stage capacity (avg block load = 1024)

typedef __attribute__((ext_vector_type(8))) short bf8;
typedef __attribute__((ext_vector_type(4))) float f32x4;

__device__ __forceinline__ float bflo(unsigned v) { return __uint_as_float(v << 16); }
__device__ __forceinline__ float bfhi(unsigned v) { return __uint_as_float(v & 0xffff0000u); }
__device__ __forceinline__ unsigned short f2bf(float f) {
    unsigned u = __float_as_uint(f);
    return (unsigned short)((u + 0x7fffu + ((u >> 16) & 1u)) >> 16);  // RNE
}
__device__ __forceinline__ unsigned packbf(float x, float y) {
    return (unsigned)f2bf(x) | ((unsigned)f2bf(y) << 16);
}
__device__ __forceinline__ unsigned addbf2(unsigned x, unsigned y) {
    return packbf(bflo(x) + bflo(y), bfhi(x) + bfhi(y));
}
__device__ __forceinline__ uint4 pack8(float4 a, float4 b) {
    uint4 o;
    o.x = packbf(a.x, a.y);
    o.y = packbf(a.z, a.w);
    o.z = packbf(b.x, b.y);
    o.w = packbf(b.z, b.w);
    return o;
}

// async global->LDS, 16 B per lane. LDS dest must be wave-uniform base + lane*16.
__device__ __forceinline__ void gload16(const unsigned short* g, unsigned short* l) {
    __builtin_amdgcn_global_load_lds(
        (const __attribute__((address_space(1))) unsigned int*)g,
        (__attribute__((address_space(3))) unsigned int*)l, 16, 0, 0);
}

// ---------------------------------------------------------------------------
// Fused: x_exp cvt (grid-stride) + 8-weight cvt + edge count+slot, one launch.
// ---------------------------------------------------------------------------
__global__ __launch_bounds__(256) void k_cvtcnt(const float4* __restrict__ xe,
                                                const float4* s0, const float4* s1,
                                                const float4* s2, const float4* s3,
                                                const float4* s4, const float4* s5,
                                                const float4* s6, const float4* s7,
                                                uint4* __restrict__ Xe,
                                                uint4* __restrict__ Wb,
                                                const int* __restrict__ edst,
                                                int* __restrict__ cnt,
                                                unsigned char* __restrict__ eslot) {
    if (blockIdx.x < 2048) {
        for (int i = blockIdx.x * 256 + threadIdx.x; i < 2560000 + 327680;
             i += 2048 * 256) {
            if (i < 2560000) {
                Xe[i] = pack8(xe[2 * i], xe[2 * i + 1]);
            } else {
                int w = i - 2560000;
                const float4* src; int off;
                if (w < 65536)       { src = s0; off = w; }
                else if (w < 131072) { src = s1; off = w - 65536; }
                else if (w < 163840) { src = s2; off = w - 131072; }
                else if (w < 196608) { src = s3; off = w - 163840; }
                else if (w < 229376) { src = s4; off = w - 196608; }
                else if (w < 262144) { src = s5; off = w - 229376; }
                else if (w < 294912) { src = s6; off = w - 262144; }
                else                 { src = s7; off = w - 294912; }
                Wb[w] = pack8(src[2 * off], src[2 * off + 1]);
            }
        }
    } else {
        int e = (blockIdx.x - 2048) * 256 + threadIdx.x;
        if (e < N_EDGES) {
            int old = atomicAdd(&cnt[edst[e]], 1);
            eslot[e] = (unsigned char)old;   // max degree ~Poisson(32) << 256
        }
    }
}

// ---------------------------------------------------------------------------
// CSR: hierarchical scan (byte-identical to r15-r19)
// ---------------------------------------------------------------------------
__global__ __launch_bounds__(256) void k_scan1(const int* __restrict__ cnt,
                                               int* __restrict__ row_ptr,
                                               int* __restrict__ bsum) {
    __shared__ int wsum[4];
    int b = blockIdx.x, t = threadIdx.x;
    int i = b * 256 + t;
    int v = (i < N_GENES) ? cnt[i] : 0;
    int lane = t & 63, wv = t >> 6;
    int x = v;
#pragma unroll
    for (int off = 1; off < 64; off <<= 1) {
        int y = __shfl_up(x, off);
        if (lane >= off) x += y;
    }
    if (lane == 63) wsum[wv] = x;
    __syncthreads();
    if (t == 0) {
        int s = 0;
        for (int w = 0; w < 4; ++w) { int tmp = wsum[w]; wsum[w] = s; s += tmp; }
    }
    __syncthreads();
    int excl = x - v + wsum[wv];
    if (i < N_GENES) row_ptr[i] = excl;
    if (t == 255) bsum[b] = excl + v;
}

__global__ void k_scan2(const int* __restrict__ bsum, int* __restrict__ boff) {
    __shared__ int wsum[2];
    int t = threadIdx.x;                      // 128
    int v = (t < SCAN_B) ? bsum[t] : 0;
    int lane = t & 63, wv = t >> 6;
    int x = v;
#pragma unroll
    for (int off = 1; off < 64; off <<= 1) {
        int y = __shfl_up(x, off);
        if (lane >= off) x += y;
    }
    if (lane == 63) wsum[wv] = x;
    __syncthreads();
    int add = (wv == 1) ? wsum[0] : 0;
    int excl = x - v + add;
    if (t < SCAN_B) boff[t] = excl;
    if (t == SCAN_B) boff[SCAN_B] = excl;
}

__global__ __launch_bounds__(256) void k_scan3(int* __restrict__ row_ptr,
                                               const int* __restrict__ boff) {
    int i = blockIdx.x * 256 + threadIdx.x;
    if (i < N_GENES) row_ptr[i] += boff[i >> 8];
    if (blockIdx.x == 0 && threadIdx.x == 0) row_ptr[N_GENES] = boff[SCAN_B];
}

// ---------------------------------------------------------------------------
// L0 PAIR GEMM + ATOMIC-FREE CSR-FILL in one dispatch. grid (8, 473).
// v7: 3-deep pipelined LDS (48 KB) + counted vmcnt(8) (best measured, R7).
// ---------------------------------------------------------------------------
__global__ __launch_bounds__(256) void k_gemm_pf(const unsigned short* __restrict__ A,
                                                 const unsigned short* __restrict__ Wl,
                                                 const unsigned short* __restrict__ Wr,
                                                 unsigned short* __restrict__ C0,
                                                 unsigned short* __restrict__ C1,
                                                 int M, int K,
                                                 const int* __restrict__ e_src,
                                                 const int* __restrict__ e_dst,
                                                 const int* __restrict__ row_ptr,
                                                 const unsigned char* __restrict__ eslot,
                                                 int* __restrict__ csr) {
    __shared__ __attribute__((aligned(16))) unsigned short As[3][128][32];
    __shared__ __attribute__((aligned(16))) unsigned short Bs[3][128][32];
    if (blockIdx.y >= 160) {   // fill path: no atomics, no barriers
        int e = ((blockIdx.y - 160) * 8 + blockIdx.x) * 256 + threadIdx.x;
        if (e < N_EDGES) {
            int d = e_dst[e];
            csr[row_ptr[d] + (int)eslot[e]] = e_src[e];
        }
        return;
    }
    int m0 = (blockIdx.x * 20 + (blockIdx.y >> 3)) * 128;
    if (m0 >= M) return;
    int sel = blockIdx.y & 7;
    const unsigned short* W = (sel < 4) ? Wl : Wr;
    unsigned short* Cp = (sel < 4) ? C0 : C1;
    int n0 = (sel & 3) * 128;
    int tid = threadIdx.x;
    int lane = tid & 63;
    int w = tid >> 6, wr = w >> 1, wc = w & 1;

    int srow = tid >> 2, sch = tid & 3;
    int rA0 = min(m0 + srow, M - 1);
    int rA1 = min(m0 + srow + 64, M - 1);
    const unsigned short* gA0 = A + (size_t)rA0 * K + sch * 8;
    const unsigned short* gA1 = A + (size_t)rA1 * K + sch * 8;
    const unsigned short* gB0 = W + (size_t)(n0 + srow) * K + sch * 8;
    const unsigned short* gB1 = W + (size_t)(n0 + srow + 64) * K + sch * 8;

    f32x4 acc[4][4];
#pragma unroll
    for (int i = 0; i < 4; ++i)
#pragma unroll
        for (int j = 0; j < 4; ++j) acc[i][j] = (f32x4){0.f, 0.f, 0.f, 0.f};

    auto stage = [&](int b, int k0) {   // literal b only -> static after inline
        unsigned short* Ab = &As[b][0][0];
        unsigned short* Bb = &Bs[b][0][0];
        gload16(gA0 + k0, Ab + tid * 8);
        gload16(gA1 + k0, Ab + 64 * 32 + tid * 8);
        gload16(gB0 + k0, Bb + tid * 8);
        gload16(gB1 + k0, Bb + 64 * 32 + tid * 8);
    };
    auto compute = [&](int b) {
        const unsigned short* Ab = &As[b][0][0];
        const unsigned short* Bb = &Bs[b][0][0];
        bf8 af[4], bff[4];
#pragma unroll
        for (int f = 0; f < 4; ++f) {
            af[f]  = *(const bf8*)(Ab + (wr * 64 + f * 16 + (lane & 15)) * 32 + (lane >> 4) * 8);
            bff[f] = *(const bf8*)(Bb + (wc * 64 + f * 16 + (lane & 15)) * 32 + (lane >> 4) * 8);
        }
#pragma unroll
        for (int i = 0; i < 4; ++i)
#pragma unroll
            for (int j = 0; j < 4; ++j)
                acc[i][j] = __builtin_amdgcn_mfma_f32_16x16x32_bf16(af[i], bff[j],
                                                                    acc[i][j], 0, 0, 0);
    };

#define PF_STEP(CB, SB, ST, VM)                                  \
    stage(SB, (ST) * 32);                                        \
    asm volatile("s_waitcnt vmcnt(" #VM ")" ::: "memory");       \
    __builtin_amdgcn_s_barrier();                                \
    __builtin_amdgcn_sched_barrier(0);                           \
    compute(CB);                                                 \
    asm volatile("s_waitcnt lgkmcnt(0)" ::: "memory");           \
    __builtin_amdgcn_s_barrier();                                \
    __builtin_amdgcn_sched_barrier(0);

    const int NT = K / 32;   // 32 for K=1024; main loop assumes NT % 3 == 2
    stage(0, 0);
    stage(1, 32);
    for (int t = 0; t + 4 < NT; t += 3) {
        PF_STEP(0, 2, t + 2, 8)
        PF_STEP(1, 0, t + 3, 8)
        PF_STEP(2, 1, t + 4, 8)
    }
    // peel: tiles NT-2 (buf 0), NT-1 (buf 1); no more staging
    asm volatile("s_waitcnt vmcnt(4)" ::: "memory");
    __builtin_amdgcn_s_barrier();
    __builtin_amdgcn_sched_barrier(0);
    compute(0);
    asm volatile("s_waitcnt lgkmcnt(0)" ::: "memory");
    __builtin_amdgcn_s_barrier();
    __builtin_amdgcn_sched_barrier(0);
    asm volatile("s_waitcnt vmcnt(0)" ::: "memory");
    __builtin_amdgcn_s_barrier();
    __builtin_amdgcn_sched_barrier(0);
    compute(1);
#undef PF_STEP

#pragma unroll
    for (int i = 0; i < 4; ++i) {
        int rb = m0 + wr * 64 + i * 16 + (lane >> 4) * 4;
#pragma unroll
        for (int j = 0; j < 4; ++j) {
            int cc = n0 + wc * 64 + j * 16 + (lane & 15);
#pragma unroll
            for (int e = 0; e < 4; ++e) {
                int r = rb + e;
                if (r < M) Cp[(size_t)r * EMB + cc] = f2bf(acc[i][j][e]);
            }
        }
    }
}

// ---------------------------------------------------------------------------
// FUSED-ADD GEMM, XCD-partitioned: grid (8, 80). BK=64 single-buffer (R6).
// ---------------------------------------------------------------------------
__global__ __launch_bounds__(256) void k_gemm_fu(const unsigned short* __restrict__ A,
                                                 const unsigned short* __restrict__ A2,
                                                 const unsigned short* __restrict__ W,
                                                 unsigned short* __restrict__ Cp,
                                                 int M, int K) {
    __shared__ __attribute__((aligned(16))) unsigned short As[2][128][32];
    __shared__ __attribute__((aligned(16))) unsigned short Bs[2][128][32];
    int m0 = (blockIdx.x * 20 + (blockIdx.y >> 2)) * 128;
    if (m0 >= M) return;
    int n0 = (blockIdx.y & 3) * 128;
    int tid = threadIdx.x;
    int lane = tid & 63;
    int w = tid >> 6, wr = w >> 1, wc = w & 1;

    int srow = tid >> 2, sch = tid & 3;
    int rA0 = min(m0 + srow, M - 1);
    int rA1 = min(m0 + srow + 64, M - 1);
    const unsigned short* gA0 = A + (size_t)rA0 * K + sch * 8;
    const unsigned short* gA1 = A + (size_t)rA1 * K + sch * 8;
    const unsigned short* hA0 = A2 + (size_t)rA0 * K + sch * 8;
    const unsigned short* hA1 = A2 + (size_t)rA1 * K + sch * 8;
    const unsigned short* gB0 = W + (size_t)(n0 + srow) * K + sch * 8;
    const unsigned short* gB1 = W + (size_t)(n0 + srow + 64) * K + sch * 8;

    f32x4 acc[4][4];
#pragma unroll
    for (int i = 0; i < 4; ++i)
#pragma unroll
        for (int j = 0; j < 4; ++j) acc[i][j] = (f32x4){0.f, 0.f, 0.f, 0.f};

    auto compute = [&](int b) {
        const unsigned short* Ab = &As[b][0][0];
        const unsigned short* Bb = &Bs[b][0][0];
        bf8 af[4], bff[4];
#pragma unroll
        for (int f = 0; f < 4; ++f) {
            af[f]  = *(const bf8*)(Ab + (wr * 64 + f * 16 + (lane & 15)) * 32 + (lane >> 4) * 8);
            bff[f] = *(const bf8*)(Bb + (wc * 64 + f * 16 + (lane & 15)) * 32 + (lane >> 4) * 8);
        }
#pragma unroll
        for (int i = 0; i < 4; ++i)
#pragma unroll
            for (int j = 0; j < 4; ++j)
                acc[i][j] = __builtin_amdgcn_mfma_f32_16x16x32_bf16(af[i], bff[j],
                                                                    acc[i][j], 0, 0, 0);
    };

    for (int k0 = 0; k0 < K; k0 += 64) {
        uint4 x00 = *(const uint4*)(gA0 + k0);
        uint4 y00 = *(const uint4*)(hA0 + k0);
        uint4 x10 = *(const uint4*)(gA1 + k0);
        uint4 y10 = *(const uint4*)(hA1 + k0);
        uint4 x01 = *(const uint4*)(gA0 + k0 + 32);
        uint4 y01 = *(const uint4*)(hA0 + k0 + 32);
        uint4 x11 = *(const uint4*)(gA1 + k0 + 32);
        uint4 y11 = *(const uint4*)(hA1 + k0 + 32);
        uint4 a00, a10, a01, a11;
        a00.x = addbf2(x00.x, y00.x); a00.y = addbf2(x00.y, y00.y);
        a00.z = addbf2(x00.z, y00.z); a00.w = addbf2(x00.w, y00.w);
        a10.x = addbf2(x10.x, y10.x); a10.y = addbf2(x10.y, y10.y);
        a10.z = addbf2(x10.z, y10.z); a10.w = addbf2(x10.w, y10.w);
        a01.x = addbf2(x01.x, y01.x); a01.y = addbf2(x01.y, y01.y);
        a01.z = addbf2(x01.z, y01.z); a01.w = addbf2(x01.w, y01.w);
        a11.x = addbf2(x11.x, y11.x); a11.y = addbf2(x11.y, y11.y);
        a11.z = addbf2(x11.z, y11.z); a11.w = addbf2(x11.w, y11.w);
        __syncthreads();
        *(uint4*)(&As[0][0][0] + tid * 8)       = a00;
        *(uint4*)(&As[0][64][0] + tid * 8)      = a10;
        *(uint4*)(&As[1][0][0] + tid * 8)       = a01;
        *(uint4*)(&As[1][64][0] + tid * 8)      = a11;
        gload16(gB0 + k0,      &Bs[0][0][0] + tid * 8);
        gload16(gB1 + k0,      &Bs[0][64][0] + tid * 8);
        gload16(gB0 + k0 + 32, &Bs[1][0][0] + tid * 8);
        gload16(gB1 + k0 + 32, &Bs[1][64][0] + tid * 8);
        __syncthreads();
        compute(0);
        compute(1);
    }

#pragma unroll
    for (int i = 0; i < 4; ++i) {
        int rb = m0 + wr * 64 + i * 16 + (lane >> 4) * 4;
#pragma unroll
        for (int j = 0; j < 4; ++j) {
            int cc = n0 + wc * 64 + j * 16 + (lane & 15);
#pragma unroll
            for (int e = 0; e < 4; ++e) {
                int r = rb + e;
                if (r < M) Cp[(size_t)r * EMB + cc] = f2bf(acc[i][j][e]);
            }
        }
    }
}

// ---------------------------------------------------------------------------
// PAIR GEMM, XCD-partitioned: grid (8, 160). BK=64 single-buffer (R6).
// ---------------------------------------------------------------------------
__global__ __launch_bounds__(256) void k_gemm_p(const unsigned short* __restrict__ A,
                                                const unsigned short* __restrict__ Wl,
                                                const unsigned short* __restrict__ Wr,
                                                unsigned short* __restrict__ C0,
                                                unsigned short* __restrict__ C1,
                                                int M, int K) {
    __shared__ __attribute__((aligned(16))) unsigned short As[2][128][32];
    __shared__ __attribute__((aligned(16))) unsigned short Bs[2][128][32];
    int m0 = (blockIdx.x * 20 + (blockIdx.y >> 3)) * 128;
    if (m0 >= M) return;
    int sel = blockIdx.y & 7;
    const unsigned short* W = (sel < 4) ? Wl : Wr;
    unsigned short* Cp = (sel < 4) ? C0 : C1;
    int n0 = (sel & 3) * 128;
    int tid = threadIdx.x;
    int lane = tid & 63;
    int w = tid >> 6, wr = w >> 1, wc = w & 1;

    int srow = tid >> 2, sch = tid & 3;
    int rA0 = min(m0 + srow, M - 1);
    int rA1 = min(m0 + srow + 64, M - 1);
    const unsigned short* gA0 = A + (size_t)rA0 * K + sch * 8;
    const unsigned short* gA1 = A + (size_t)rA1 * K + sch * 8;
    const unsigned short* gB0 = W + (size_t)(n0 + srow) * K + sch * 8;
    const unsigned short* gB1 = W + (size_t)(n0 + srow + 64) * K + sch * 8;

    f32x4 acc[4][4];
#pragma unroll
    for (int i = 0; i < 4; ++i)
#pragma unroll
        for (int j = 0; j < 4; ++j) acc[i][j] = (f32x4){0.f, 0.f, 0.f, 0.f};

    auto compute = [&](int b) {
        const unsigned short* Ab = &As[b][0][0];
        const unsigned short* Bb = &Bs[b][0][0];
        bf8 af[4], bff[4];
#pragma unroll
        for (int f = 0; f < 4; ++f) {
            af[f]  = *(const bf8*)(Ab + (wr * 64 + f * 16 + (lane & 15)) * 32 + (lane >> 4) * 8);
            bff[f] = *(const bf8*)(Bb + (wc * 64 + f * 16 + (lane & 15)) * 32 + (lane >> 4) * 8);
        }
#pragma unroll
        for (int i = 0; i < 4; ++i)
#pragma unroll
            for (int j = 0; j < 4; ++j)
                acc[i][j] = __builtin_amdgcn_mfma_f32_16x16x32_bf16(af[i], bff[j],
                                                                    acc[i][j], 0, 0, 0);
    };

    for (int k0 = 0; k0 < K; k0 += 64) {
        __syncthreads();
        gload16(gA0 + k0,      &As[0][0][0] + tid * 8);
        gload16(gA1 + k0,      &As[0][64][0] + tid * 8);
        gload16(gA0 + k0 + 32, &As[1][0][0] + tid * 8);
        gload16(gA1 + k0 + 32, &As[1][64][0] + tid * 8);
        gload16(gB0 + k0,      &Bs[0][0][0] + tid * 8);
        gload16(gB1 + k0,      &Bs[0][64][0] + tid * 8);
        gload16(gB0 + k0 + 32, &Bs[1][0][0] + tid * 8);
        gload16(gB1 + k0 + 32, &Bs[1][64][0] + tid * 8);
        __syncthreads();
        compute(0);
        compute(1);
    }

#pragma unroll
    for (int i = 0; i < 4; ++i) {
        int rb = m0 + wr * 64 + i * 16 + (lane >> 4) * 4;
#pragma unroll
        for (int j = 0; j < 4; ++j) {
            int cc = n0 + wc * 64 + j * 16 + (lane & 15);
#pragma unroll
            for (int e = 0; e < 4; ++e) {
                int r = rb + e;
                if (r < M) Cp[(size_t)r * EMB + cc] = f2bf(acc[i][j][e]);
            }
        }
    }
}

// ---------------------------------------------------------------------------
// TRIPLE GEMM: L1 pair (A1 bf16, gload_lds) + Wf single (A2 fp32, reg-staged),
// grid (8, 240). BK=64 single-buffer (R6); B always via gload_lds.
// ---------------------------------------------------------------------------
__global__ __launch_bounds__(256) void k_gemm_3(const unsigned short* __restrict__ A1,
                                                const float* __restrict__ A2,
                                                const unsigned short* __restrict__ Wl,
                                                const unsigned short* __restrict__ Wr,
                                                const unsigned short* __restrict__ Wf,
                                                unsigned short* __restrict__ C0,
                                                unsigned short* __restrict__ C1,
                                                unsigned short* __restrict__ CF,
                                                int M) {
    const int K = 512;
    __shared__ __attribute__((aligned(16))) unsigned short As[2][128][32];
    __shared__ __attribute__((aligned(16))) unsigned short Bs[2][128][32];
    int y = blockIdx.y;
    bool fpath = (y >= 160);
    int m0, n0;
    const unsigned short* W;
    unsigned short* Cp;
    if (!fpath) {
        m0 = (blockIdx.x * 20 + (y >> 3)) * 128;
        int sel = y & 7;
        W = (sel < 4) ? Wl : Wr;
        Cp = (sel < 4) ? C0 : C1;
        n0 = (sel & 3) * 128;
    } else {
        int y2 = y - 160;
        m0 = (blockIdx.x * 20 + (y2 >> 2)) * 128;
        n0 = (y2 & 3) * 128;
        W = Wf;
        Cp = CF;
    }
    if (m0 >= M) return;
    int tid = threadIdx.x;
    int lane = tid & 63;
    int w = tid >> 6, wr = w >> 1, wc = w & 1;

    int srow = tid >> 2, sch = tid & 3;
    int rA0 = min(m0 + srow, M - 1);
    int rA1 = min(m0 + srow + 64, M - 1);
    const unsigned short* gA0 = A1 + (size_t)rA0 * K + sch * 8;
    const unsigned short* gA1 = A1 + (size_t)rA1 * K + sch * 8;
    const float* fA0 = A2 + (size_t)rA0 * K + sch * 8;
    const float* fA1 = A2 + (size_t)rA1 * K + sch * 8;
    const unsigned short* gB0 = W + (size_t)(n0 + srow) * K + sch * 8;
    const unsigned short* gB1 = W + (size_t)(n0 + srow + 64) * K + sch * 8;

    f32x4 acc[4][4];
#pragma unroll
    for (int i = 0; i < 4; ++i)
#pragma unroll
        for (int j = 0; j < 4; ++j) acc[i][j] = (f32x4){0.f, 0.f, 0.f, 0.f};

    auto compute = [&](int b) {
        const unsigned short* Ab = &As[b][0][0];
        const unsigned short* Bb = &Bs[b][0][0];
        bf8 af[4], bff[4];
#pragma unroll
        for (int f = 0; f < 4; ++f) {
            af[f]  = *(const bf8*)(Ab + (wr * 64 + f * 16 + (lane & 15)) * 32 + (lane >> 4) * 8);
            bff[f] = *(const bf8*)(Bb + (wc * 64 + f * 16 + (lane & 15)) * 32 + (lane >> 4) * 8);
        }
#pragma unroll
        for (int i = 0; i < 4; ++i)
#pragma unroll
            for (int j = 0; j < 4; ++j)
                acc[i][j] = __builtin_amdgcn_mfma_f32_16x16x32_bf16(af[i], bff[j],
                                                                    acc[i][j], 0, 0, 0);
    };

    for (int k0 = 0; k0 < K; k0 += 64) {
        float4 f0a, f0b, f0c, f0d, f1a, f1b, f1c, f1d;
        if (fpath) {  // block-uniform branch: fp32 loads issued before barrier
            f0a = *(const float4*)(fA0 + k0);      f0b = *(const float4*)(fA0 + k0 + 4);
            f1a = *(const float4*)(fA1 + k0);      f1b = *(const float4*)(fA1 + k0 + 4);
            f0c = *(const float4*)(fA0 + k0 + 32); f0d = *(const float4*)(fA0 + k0 + 36);
            f1c = *(const float4*)(fA1 + k0 + 32); f1d = *(const float4*)(fA1 + k0 + 36);
        }
        __syncthreads();
        if (fpath) {
            *(uint4*)(&As[0][0][0] + tid * 8)  = pack8(f0a, f0b);
            *(uint4*)(&As[0][64][0] + tid * 8) = pack8(f1a, f1b);
            *(uint4*)(&As[1][0][0] + tid * 8)  = pack8(f0c, f0d);
            *(uint4*)(&As[1][64][0] + tid * 8) = pack8(f1c, f1d);
        } else {
            gload16(gA0 + k0,      &As[0][0][0] + tid * 8);
            gload16(gA1 + k0,      &As[0][64][0] + tid * 8);
            gload16(gA0 + k0 + 32, &As[1][0][0] + tid * 8);
            gload16(gA1 + k0 + 32, &As[1][64][0] + tid * 8);
        }
        gload16(gB0 + k0,      &Bs[0][0][0] + tid * 8);
        gload16(gB1 + k0,      &Bs[0][64][0] + tid * 8);
        gload16(gB0 + k0 + 32, &Bs[1][0][0] + tid * 8);
        gload16(gB1 + k0 + 32, &Bs[1][64][0] + tid * 8);
        __syncthreads();
        compute(0);
        compute(1);
    }

#pragma unroll
    for (int i = 0; i < 4; ++i) {
        int rb = m0 + wr * 64 + i * 16 + (lane >> 4) * 4;
#pragma unroll
        for (int j = 0; j < 4; ++j) {
            int cc = n0 + wc * 64 + j * 16 + (lane & 15);
#pragma unroll
            for (int e = 0; e < 4; ++e) {
                int r = rb + e;
                if (r < M) Cp[(size_t)r * EMB + cc] = f2bf(acc[i][j][e]);
            }
        }
    }
}

// ---------------------------------------------------------------------------
// Sage body v2, XCD-SLICED: slice (128 B cols) pinned to XCD via grid x-dim.
// Block = 32 nodes x 8 lanes; lane l covers uint4 word slice*8+l (16 B).
// 8-deep gather batches (measured best; 16-deep regressed, R9).
// ---------------------------------------------------------------------------
template <int OUTF32>
__device__ __forceinline__ void sage_body(const unsigned short* yl,
                                          const unsigned short* yr,
                                          const float* bl,
                                          const int* row_ptr,
                                          const int* csr,
                                          void* outp, int slice, int nblk,
                                          int* sIdx) {
    int g = threadIdx.x >> 3;            // node in block: 0..31
    int l = threadIdx.x & 7;             // lane in group: 0..7
    int node = nblk * 32 + g;
    int w = slice * 8 + l;               // uint4 word index 0..63
    int s32 = row_ptr[nblk * 32];
    int e32 = row_ptr[nblk * 32 + 32];
    int nIdx = e32 - s32;
    bool lds_ok = (nIdx <= IDX_CAP);
    if (lds_ok) {
        for (int i = threadIdx.x; i < nIdx; i += 256) sIdx[i] = csr[s32 + i];
    }
    __syncthreads();
    int s = row_ptr[node], e = row_ptr[node + 1];
    int deg = e - s;
    const char* Yb = (const char*)yl;    // row stride 1024 B
    unsigned lb = (unsigned)(w << 4);
    float ac[8];
#pragma unroll
    for (int q = 0; q < 8; ++q) ac[q] = 0.f;
    if (lds_ok) {
        int lp = s - s32;
        int p = 0;
        for (; p + 8 <= deg; p += 8) {
            int j[8];
#pragma unroll
            for (int q = 0; q < 8; ++q) j[q] = sIdx[lp + p + q];
            uint4 v[8];
#pragma unroll
            for (int q = 0; q < 8; ++q)
                v[q] = *(const uint4*)(Yb + (((unsigned)j[q] << 10) + lb));
#pragma unroll
            for (int q = 0; q < 8; ++q) {
                ac[0] += bflo(v[q].x); ac[1] += bfhi(v[q].x);
                ac[2] += bflo(v[q].y); ac[3] += bfhi(v[q].y);
                ac[4] += bflo(v[q].z); ac[5] += bfhi(v[q].z);
                ac[6] += bflo(v[q].w); ac[7] += bfhi(v[q].w);
            }
        }
        for (; p < deg; ++p) {
            int j = sIdx[lp + p];
            uint4 v = *(const uint4*)(Yb + (((unsigned)j << 10) + lb));
            ac[0] += bflo(v.x); ac[1] += bfhi(v.x);
            ac[2] += bflo(v.y); ac[3] += bfhi(v.y);
            ac[4] += bflo(v.z); ac[5] += bfhi(v.z);
            ac[6] += bflo(v.w); ac[7] += bfhi(v.w);
        }
    } else {  // overflow fallback (never expected for this input)
        for (int p = s; p < e; ++p) {
            int j = csr[p];
            uint4 v = *(const uint4*)(Yb + (((unsigned)j << 10) + lb));
            ac[0] += bflo(v.x); ac[1] += bfhi(v.x);
            ac[2] += bflo(v.y); ac[3] += bfhi(v.y);
            ac[4] += bflo(v.z); ac[5] += bfhi(v.z);
            ac[6] += bflo(v.w); ac[7] += bfhi(v.w);
        }
    }
    float inv = 1.f / fmaxf((float)deg, 1.f);
    uint4 vr = ((const uint4*)yr)[(size_t)node * 64 + w];
    float4 bA = ((const float4*)bl)[2 * w];
    float4 bB = ((const float4*)bl)[2 * w + 1];
    float o[8];
    o[0] = ac[0] * inv + bA.x + bflo(vr.x);
    o[1] = ac[1] * inv + bA.y + bfhi(vr.x);
    o[2] = ac[2] * inv + bA.z + bflo(vr.y);
    o[3] = ac[3] * inv + bA.w + bfhi(vr.y);
    o[4] = ac[4] * inv + bB.x + bflo(vr.z);
    o[5] = ac[5] * inv + bB.y + bfhi(vr.z);
    o[6] = ac[6] * inv + bB.z + bflo(vr.w);
    o[7] = ac[7] * inv + bB.w + bfhi(vr.w);
#pragma unroll
    for (int q = 0; q < 8; ++q) o[q] = o[q] > 0.f ? o[q] : expm1f(o[q]);
    if (OUTF32) {
        float4* O = (float4*)outp;
        O[(size_t)node * 128 + 2 * w]     = make_float4(o[0], o[1], o[2], o[3]);
        O[(size_t)node * 128 + 2 * w + 1] = make_float4(o[4], o[5], o[6], o[7]);
    } else {
        uint4 ov;
        ov.x = packbf(o[0], o[1]);
        ov.y = packbf(o[2], o[3]);
        ov.z = packbf(o[4], o[5]);
        ov.w = packbf(o[6], o[7]);
        ((uint4*)outp)[(size_t)node * 64 + w] = ov;
    }
}

// grid (8, 625): x = slice/XCD, y = node block (32 nodes)
template <int OUTF32>
__global__ __launch_bounds__(256) void k_sage_b(const unsigned short* __restrict__ yl,
                                                const unsigned short* __restrict__ yr,
                                                const float* __restrict__ bl,
                                                const int* __restrict__ row_ptr,
                                                const int* __restrict__ csr,
                                                void* __restrict__ outp) {
    __shared__ int sIdx[IDX_CAP];
    sage_body<OUTF32>(yl, yr, bl, row_ptr, csr, outp, blockIdx.x, blockIdx.y, sIdx);
}

// ---------------------------------------------------------------------------
// LN body: LN(bf16 X + fp32 bias) + act -> bf16.
// ---------------------------------------------------------------------------
template <int ACT>
__device__ __forceinline__ void ln_body(const unsigned short* X,
                                        const float* bias, const float* g,
                                        const float* b, unsigned short* Y, int row) {
    __shared__ float red[8];
    int t = threadIdx.x;
    unsigned v = *(const unsigned*)(X + (size_t)row * EMB + 2 * t);
    float x0 = bflo(v) + bias[2 * t];
    float x1 = bfhi(v) + bias[2 * t + 1];
    float s = x0 + x1;
    float q = x0 * x0 + x1 * x1;
#pragma unroll
    for (int off = 32; off > 0; off >>= 1) {
        s += __shfl_down(s, off);
        q += __shfl_down(q, off);
    }
    int wave = t >> 6, lane = t & 63;
    if (lane == 0) { red[wave * 2] = s; red[wave * 2 + 1] = q; }
    __syncthreads();
    if (t == 0) {
        float ts = 0.f, tq = 0.f;
        for (int w = 0; w < 4; w++) { ts += red[w * 2]; tq += red[w * 2 + 1]; }
        red[0] = ts; red[1] = tq;
    }
    __syncthreads();
    float mu   = red[0] * (1.0f / 512.0f);
    float var  = red[1] * (1.0f / 512.0f) - mu * mu;
    float rstd = rsqrtf(var + LN_EPS);
    float y0 = (x0 - mu) * rstd * g[2 * t]     + b[2 * t];
    float y1 = (x1 - mu) * rstd * g[2 * t + 1] + b[2 * t + 1];
    if (ACT == 0) {  // exact GELU
        y0 = 0.5f * y0 * (1.0f + erff(y0 * 0.70710678118654752440f));
        y1 = 0.5f * y1 * (1.0f + erff(y1 * 0.70710678118654752440f));
    } else {         // SiLU
        y0 = y0 / (1.0f + expf(-y0));
        y1 = y1 / (1.0f + expf(-y1));
    }
    ((unsigned*)Y)[(size_t)row * (EMB / 2) + t] = packbf(y0, y1);
}

template <int ACT>
__global__ __launch_bounds__(256) void k_ln_b(const unsigned short* __restrict__ X,
                                              const float* __restrict__ bias,
                                              const float* __restrict__ g,
                                              const float* __restrict__ b,
                                              unsigned short* __restrict__ Y) {
    ln_body<ACT>(X, bias, g, b, Y, blockIdx.x);
}

// ---------------------------------------------------------------------------
// MERGED: sliced sage1 (C0,C1 -> Pd) + LN<0> (F0 -> actA).
// grid (8, 3125): y < 625 -> sage(slice=x, nblk=y);
// y >= 625 -> LN row (y-625)*8 + x  (covers 0..19999).
// ---------------------------------------------------------------------------
__global__ __launch_bounds__(256) void k_sageln(const unsigned short* __restrict__ C0,
                                                const unsigned short* __restrict__ C1,
                                                const float* __restrict__ bl1,
                                                const int* __restrict__ row_ptr,
                                                const int* __restrict__ csr,
                                                unsigned short* __restrict__ Pd,
                                                const unsigned short* __restrict__ F0,
                                                const float* __restrict__ bf_,
                                                const float* __restrict__ g1,
                                                const float* __restrict__ b1,
                                                unsigned short* __restrict__ fout) {
    __shared__ int sIdx[IDX_CAP];
    if (blockIdx.y < 625) {
        sage_body<0>(C0, C1, bl1, row_ptr, csr, Pd, blockIdx.x, blockIdx.y, sIdx);
    } else {
        ln_body<0>(F0, bf_, g1, b1, fout, (blockIdx.y - 625) * 8 + blockIdx.x);
    }
}

// ---------------------------------------------------------------------------
extern "C" void kernel_launch(void* const* d_in, const int* in_sizes, int n_in,
                              void* d_out, int out_size, void* d_ws, size_t ws_size,
                              hipStream_t stream) {
    const float* x_found = (const float*)d_in[0];
    const float* x_exp   = (const float*)d_in[1];
    const int*   ppi     = (const int*)d_in[2];
    const float* Wl0 = (const float*)d_in[3];
    const float* bl0 = (const float*)d_in[4];
    const float* Wr0 = (const float*)d_in[5];
    const float* Wl1 = (const float*)d_in[6];
    const float* bl1 = (const float*)d_in[7];
    const float* Wr1 = (const float*)d_in[8];
    const float* Wf  = (const float*)d_in[9];
    const float* bf_ = (const float*)d_in[10];
    const float* g1  = (const float*)d_in[11];
    const float* b1  = (const float*)d_in[12];
    const float* Wfu = (const float*)d_in[13];
    const float* bfu = (const float*)d_in[14];
    const float* g2  = (const float*)d_in[15];
    const float* b2  = (const float*)d_in[16];
    const float* Wl2 = (const float*)d_in[17];
    const float* bl2 = (const float*)d_in[18];
    const float* Wr2 = (const float*)d_in[19];

    const int* e_src = ppi;
    const int* e_dst = ppi + N_EDGES;

    char* ws = (char*)d_ws;
    unsigned short* C0   = (unsigned short*)(ws);                 // 20,480,000 B
    unsigned short* C1   = (unsigned short*)(ws + 20480000);      // 20,480,000 B
    unsigned short* actA = (unsigned short*)(ws + 40960000);      // 20,480,000 B
    int* cnt     = (int*)(ws + 61440000);   // 80,000 B
    int* row_ptr = (int*)(ws + 61520000);   // 80,004 B (padded)
    unsigned char* eslot = (unsigned char*)(ws + 61600064);  // 640,000 B
    int* csr     = (int*)(ws + 62240064);   // 2,560,000 B -> 64,800,064
    unsigned short* Wb = (unsigned short*)(ws + 64800064);        // 5,242,880 B
    unsigned short* Wl0b = Wb;
    unsigned short* Wr0b = Wb + 524288;
    unsigned short* Wl1b = Wb + 1048576;
    unsigned short* Wr1b = Wb + 1310720;
    unsigned short* Wfb  = Wb + 1572864;
    unsigned short* Wfub = Wb + 1835008;
    unsigned short* Wl2b = Wb + 2097152;
    unsigned short* Wr2b = Wb + 2359296;
    int* bsum = (int*)(ws + 70042944);      // 320 B
    int* boff = (int*)(ws + 70043264);      // 324 B -> end ~70.1 MB

    unsigned short* Xe = (unsigned short*)d_out;             // full d_out (until L0 done)
    unsigned short* Pd = (unsigned short*)d_out;             // h2 scratch (lower half)
    unsigned short* F0 = (unsigned short*)d_out + 10240000;  // Wf out (upper half)

    // ---- fused cvt (x_exp + weights) + edge count+slot; then scan
    hipMemsetAsync(cnt, 0, N_GENES * sizeof(int), stream);
    k_cvtcnt<<<4548, 256, 0, stream>>>((const float4*)x_exp,
                                       (const float4*)Wl0, (const float4*)Wr0,
                                       (const float4*)Wl1, (const float4*)Wr1,
                                       (const float4*)Wf,  (const float4*)Wfu,
                                       (const float4*)Wl2, (const float4*)Wr2,
                                       (uint4*)Xe, (uint4*)Wb, e_dst, cnt, eslot);
    k_scan1<<<SCAN_B, 256, 0, stream>>>(cnt, row_ptr, bsum);
    k_scan2<<<1, 128, 0, stream>>>(bsum, boff);
    k_scan3<<<SCAN_B, 256, 0, stream>>>(row_ptr, boff);

    dim3 gg(8, 80);    // fused-add GEMM
    dim3 gp(8, 160);   // pair GEMM
    dim3 g3(8, 240);   // triple GEMM (pair + Wf)
    dim3 gpf(8, 473);  // L0 pair GEMM + atomic-free CSR fill
    dim3 gs(8, 625);   // XCD-sliced sage
    dim3 gsl(8, 3125); // XCD-sliced sage + LN merge

    // ---- layer 0 (K=1024) fused with atomic-free CSR fill
    k_gemm_pf<<<gpf, 256, 0, stream>>>(Xe, Wl0b, Wr0b, C0, C1, N_GENES, N_CELLS,
                                       e_src, e_dst, row_ptr, eslot, csr);
    k_sage_b<0><<<gs, 256, 0, stream>>>(C0, C1, bl0, row_ptr, csr, actA);          // h1
    // Xe dead from here on.

    // ---- merged: L1 pair (A=actA) + foundation Wf (A=x_found) -> C0,C1,F0
    k_gemm_3<<<g3, 256, 0, stream>>>(actA, x_found, Wl1b, Wr1b, Wfb,
                                     C0, C1, F0, N_GENES);
    // ---- merged: sliced sage1 -> Pd  +  LN<0>(F0) -> actA (f)
    k_sageln<<<gsl, 256, 0, stream>>>(C0, C1, bl1, row_ptr, csr,
                                      Pd, F0, bf_, g1, b1, actA);

    // ---- fusion (fused add inside GEMM): fo = SiLU(LN((h2 + f) @ Wfu^T + bfu))
    k_gemm_fu<<<gg, 256, 0, stream>>>(Pd, actA, Wfub, C0, N_GENES, EMB);
    k_ln_b<1><<<N_GENES, 256, 0, stream>>>(C0, bfu, g2, b2, actA);                 // fo

    // ---- final SAGE -> d_out (fp32; Pd and F0 both dead)
    k_gemm_p<<<gp, 256, 0, stream>>>(actA, Wl2b, Wr2b, C0, C1, N_GENES, EMB);
    k_sage_b<1><<<gs, 256, 0, stream>>>(C0, C1, bl2, row_ptr, csr, (float*)d_out);
}